// Round 11
// baseline (330.104 us; speedup 1.0000x reference)
//
#include <hip/hip_runtime.h>

// Problem constants
constexpr int GG    = 512;          // graphs
constexpr int NPG   = 128;          // nodes per graph
constexpr int FIN   = 64;
constexpr int DD    = 128;
constexpr int RR    = 4;
constexpr int NN    = GG * NPG;     // 65536 nodes
constexpr int EE    = 1572864;      // edges
constexpr int NRSEG = NN * RR;      // 262144 segments (key = r*NN + dst)
constexpr int BCAP  = 7680;         // per-bucket capacity in k_binB (avg 6144, sd ~78)

typedef __attribute__((ext_vector_type(8))) short bf16x8;
typedef __attribute__((ext_vector_type(4))) float f32x4;
typedef unsigned short u16;
typedef unsigned int   u32;

__device__ __forceinline__ u32 bf16_rne(float x) {
    u32 u = __float_as_uint(x);
    return (u + 0x7FFFu + ((u >> 16) & 1u)) >> 16;
}

// async global->LDS DMA, 16 B per lane; LDS side must be uniform-base + lane*16
__device__ __forceinline__ void gl_lds16(const void* g, void* l) {
    __builtin_amdgcn_global_load_lds((const __attribute__((address_space(1))) u32*)g,
                                     (__attribute__((address_space(3))) u32*)l, 16, 0, 0);
}

// ---------------- fused front: embed + bucket-count + prep + out-zero --------
// blocks [0,1024): embed | [1024,1216): bucket-count | [1216,1856): prep |
// [1856,1920): zero out. NOTE: zero-out covers ALL GG*DD floats — harness
// re-poisons d_out to 0xAA each replay; atomicMax keeps poison otherwise.

__global__ __launch_bounds__(256, 2) void k_front(const float* __restrict__ x,
                                                  const float* __restrict__ W_emb,
                                                  const float* __restrict__ b_emb,
                                                  u16* __restrict__ h,
                                                  const int* __restrict__ ei,
                                                  const int* __restrict__ ea,
                                                  u32* __restrict__ bc,
                                                  const float* __restrict__ W_root,
                                                  const float* __restrict__ W_rel,
                                                  u16* __restrict__ wtH,
                                                  float* __restrict__ outF) {
    __shared__ float sA[16 * 64];
    __shared__ float sB[16 * 128];
    __shared__ int bh[256];
    int tid = threadIdx.x;
    int bid = blockIdx.x;

    if (bid < 1024) {
        // ---- embed: h = bf16(x @ W_emb + b_emb) ----
        int tx = tid & 31, ty = tid >> 5;
        int row0 = bid * 64;
        float4 bv = *(const float4*)&b_emb[tx * 4];
        float acc[8][4];
#pragma unroll
        for (int i = 0; i < 8; ++i) { acc[i][0]=bv.x; acc[i][1]=bv.y; acc[i][2]=bv.z; acc[i][3]=bv.w; }
        for (int kb = 0; kb < 4; ++kb) {
            {
                int rr = tid >> 2, kq = tid & 3;
                float4 v = *(const float4*)&x[(row0 + rr) * FIN + kb * 16 + kq * 4];
                sA[(kq*4+0)*64 + rr] = v.x;
                sA[(kq*4+1)*64 + rr] = v.y;
                sA[(kq*4+2)*64 + rr] = v.z;
                sA[(kq*4+3)*64 + rr] = v.w;
            }
#pragma unroll
            for (int i = 0; i < 2; ++i) {
                int f = tid + i * 256;
                *(float4*)&sB[f * 4] = *(const float4*)&W_emb[kb * 16 * 128 + f * 4];
            }
            __syncthreads();
#pragma unroll
            for (int kk = 0; kk < 16; ++kk) {
                float4 a0 = *(const float4*)&sA[kk * 64 + ty * 4];
                float4 a1 = *(const float4*)&sA[kk * 64 + 32 + ty * 4];
                float4 bq = *(const float4*)&sB[kk * 128 + tx * 4];
                float ar[8] = {a0.x,a0.y,a0.z,a0.w,a1.x,a1.y,a1.z,a1.w};
#pragma unroll
                for (int i = 0; i < 8; ++i) {
                    acc[i][0] = fmaf(ar[i], bq.x, acc[i][0]);
                    acc[i][1] = fmaf(ar[i], bq.y, acc[i][1]);
                    acc[i][2] = fmaf(ar[i], bq.z, acc[i][2]);
                    acc[i][3] = fmaf(ar[i], bq.w, acc[i][3]);
                }
            }
            __syncthreads();
        }
#pragma unroll
        for (int i = 0; i < 8; ++i) {
            int row = (i < 4) ? (ty * 4 + i) : (32 + ty * 4 + (i - 4));
            u32 s0 = bf16_rne(acc[i][0]), s1 = bf16_rne(acc[i][1]);
            u32 s2 = bf16_rne(acc[i][2]), s3 = bf16_rne(acc[i][3]);
            *(uint2*)&h[(row0 + row) * DD + tx * 4] = make_uint2(s0 | (s1 << 16), s2 | (s3 << 16));
        }
    } else if (bid < 1216) {
        // ---- bucket-count: LDS hist of bucket = (a<<6)|(dst>>10) ----
        int e0 = (bid - 1024) * 8192;          // 192 blocks cover EE exactly
        bh[tid] = 0;
        __syncthreads();
        for (int i = 0; i < 32; ++i) {
            int e = e0 + i * 256 + tid;
            int dst = ei[EE + e];
            int a   = ea[e];
            atomicAdd(&bh[(a << 6) | (dst >> 10)], 1);
        }
        __syncthreads();
        atomicAdd(&bc[tid], (u32)bh[tid]);
    } else if (bid < 1856) {
        // ---- prep: transpose weights to bf16, wt[mat*16384 + n*128 + k] ----
        int idx = (bid - 1216) * 256 + tid;    // covers 10*16384
        int mat = idx >> 14;
        int rem = idx & 16383;
        int n = rem >> 7, k = rem & 127;
        int l = mat / 5, m5 = mat - l * 5;
        float v = (m5 == 0) ? W_root[l * 16384 + k * 128 + n]
                            : W_rel[((l * RR + (m5 - 1)) * 128 + k) * 128 + n];
        wtH[idx] = (u16)bf16_rne(v);
    } else {
        // ---- zero out (fused maxpool init; relu >= 0): float4 covers GG*DD ----
        int i = (bid - 1856) * 256 + tid;      // 16384 threads x 4 floats = 65536
        *(float4*)&outF[i * 4] = make_float4(0.f, 0.f, 0.f, 0.f);
    }
}

// ---------------- tiny scan: 256 bucket totals -> bases ----------------------

__global__ __launch_bounds__(256) void k_mini(const u32* __restrict__ bc,
                                              u32* __restrict__ bcur,
                                              u32* __restrict__ bbase) {
    __shared__ int ts[256];
    int tid = threadIdx.x;
    int v = (int)bc[tid];
    ts[tid] = v;
    __syncthreads();
    for (int o = 1; o < 256; o <<= 1) {
        int t = (tid >= o) ? ts[tid - o] : 0;
        __syncthreads();
        ts[tid] += t;
        __syncthreads();
    }
    u32 ex = (u32)(ts[tid] - v);
    bcur[tid]  = ex;
    bbase[tid] = ex;
}

// ---------------- bucketed scatter phase A: bin edges by bucket --------------
// Block owns 8192 edges; LDS histogram, one global atomic per (block,bucket)
// reserves a contiguous run in binned -> line-local writes.

__global__ __launch_bounds__(256) void k_binA(const int* __restrict__ ei,
                                              const int* __restrict__ ea,
                                              u32* __restrict__ bcur,
                                              u32* __restrict__ binned) {
    __shared__ int bh[256];
    __shared__ int lcur[256];
    int tid = threadIdx.x;
    int e0 = blockIdx.x * 8192;                // 192 blocks cover EE exactly
    bh[tid] = 0;
    __syncthreads();
    for (int i = 0; i < 32; ++i) {
        int e = e0 + i * 256 + tid;
        int dst = ei[EE + e];
        int a   = ea[e];
        atomicAdd(&bh[(a << 6) | (dst >> 10)], 1);
    }
    __syncthreads();
    lcur[tid] = (int)atomicAdd(&bcur[tid], (u32)bh[tid]);
    __syncthreads();
    for (int i = 0; i < 32; ++i) {
        int e = e0 + i * 256 + tid;
        int src = ei[e];
        int dst = ei[EE + e];
        int a   = ea[e];
        int pos = atomicAdd(&lcur[(a << 6) | (dst >> 10)], 1);
        binned[pos] = (u32)src | ((u32)dst << 16);
    }
}

// ---------------- bucketed scatter phase B: sort + emit offs/inv -------------
// One block per bucket. Subkey = dst&1023. LDS count + prefix -> writes the
// 1024 segment offsets (offs) and inverse counts (inv) for its key range,
// then rank-scatters srcs (u16) via LDS staging (contiguous flush).

__global__ __launch_bounds__(256) void k_binB(const u32* __restrict__ binned,
                                              const u32* __restrict__ bbase,
                                              int* __restrict__ offs,
                                              float* __restrict__ inv,
                                              u16* __restrict__ sorted) {
    __shared__ int pc[1024];
    __shared__ int ts[256];
    __shared__ u16 stg[BCAP];
    int tid = threadIdx.x;
    int b = blockIdx.x;
    int p0 = (int)bbase[b];
    int p1 = (b == 255) ? EE : (int)bbase[b + 1];
    int cnt = p1 - p0;
    bool fits = (cnt <= BCAP);

#pragma unroll
    for (int i = 0; i < 4; ++i) pc[i * 256 + tid] = 0;
    __syncthreads();
    for (int i = tid; i < cnt; i += 256) {
        u32 rec = binned[p0 + i];
        atomicAdd(&pc[(rec >> 16) & 1023], 1);
    }
    __syncthreads();
    int v[4], s = 0;
#pragma unroll
    for (int i = 0; i < 4; ++i) { v[i] = pc[tid * 4 + i]; s += v[i]; }
    ts[tid] = s;
    __syncthreads();
    for (int o = 1; o < 256; o <<= 1) {
        int t = (tid >= o) ? ts[tid - o] : 0;
        __syncthreads();
        ts[tid] += t;
        __syncthreads();
    }
    int ex = ts[tid] - s;
    // emit offs + inv for this thread's 4 keys, and store local prefix in pc
    {
        int4 o4; float4 i4;
        int e = ex;
#pragma unroll
        for (int i = 0; i < 4; ++i) {
            (&o4.x)[i] = p0 + e;
            (&i4.x)[i] = 1.0f / (float)(v[i] > 0 ? v[i] : 1);
            e += v[i];
        }
        *(int4*)&offs[(b << 10) + tid * 4]  = o4;
        *(float4*)&inv[(b << 10) + tid * 4] = i4;
    }
    __syncthreads();                            // counts consumed
#pragma unroll
    for (int i = 0; i < 4; ++i) { pc[tid * 4 + i] = ex; ex += v[i]; }
    __syncthreads();
    if (fits) {
        for (int i = tid; i < cnt; i += 256) {
            u32 rec = binned[p0 + i];
            int pos = atomicAdd(&pc[(rec >> 16) & 1023], 1);
            stg[pos] = (u16)(rec & 0xFFFFu);
        }
        __syncthreads();
        for (int i = tid; i < cnt; i += 256) sorted[p0 + i] = stg[i];
    } else {
        for (int i = tid; i < cnt; i += 256) {
            u32 rec = binned[p0 + i];
            int pos = atomicAdd(&pc[(rec >> 16) & 1023], 1);
            sorted[p0 + pos] = (u16)(rec & 0xFFFFu);
        }
    }
}

// ---------------- fused RGCN layer ----------------
// 256 threads = 4 waves; wave owns a 16-node M-strip.
// Gather folded into the MFMA quarter loop: quarter q of matrix m processes
// gather-node t2=q of relation m (fH writes target mat m+1; AH for mat m is
// already in regs) -> gather loads overlap MFMA/stage instead of running in an
// exposed phase. Edge loads use exact 8/4/2/1 batches (Poisson(6) segment
// sizes: the old serial tail dominated). sIdx dbuf prefetch one relation
// ahead; inv prestaged; offs hoisted to loadA point.
// LDS: fH 16K + sQ 16K + sIdx 6K + sInv 1K + sMeta = 40000 B -> 4 blocks/CU.

constexpr int ICAP = 192;   // per-wave sIdx capacity (wcnt avg 96, sd ~10)

template<int LAST>
__global__ __launch_bounds__(256, 4) void k_layer(const u16* __restrict__ hin,
                                                  u16* __restrict__ houtH,
                                                  float* __restrict__ outF,
                                                  const u16* __restrict__ wtH,
                                                  const float* __restrict__ bias,
                                                  const u16* __restrict__ sorted,
                                                  const int* __restrict__ offs,
                                                  const float* __restrict__ inv) {
    __shared__ __align__(16) u16 fH[4 * 2048];   // 16 KB A-frags (swizzled, wave-private)
    __shared__ __align__(16) u16 sQ[2][4096];    // 2 x 8 KB B k-quarter buffers
    __shared__ int   sIdx[2][4 * ICAP];          // 6 KB dbuf gather indices
    __shared__ float sInv[4 * 64];               // 1 KB prestaged inverse counts
    __shared__ int   sMeta[2][4][2];             // (w0, w1) per buf/wave

    int tid  = threadIdx.x;
    int wave = tid >> 6, lane = tid & 63;
    int mm   = lane & 15;            // MFMA m/n lane; gather col-octet
    int qd   = lane >> 4;            // MFMA quad; gather quarter (node group)
    int row0 = blockIdx.x * 64;
    int wbU  = wave * 2048;          // fH wave base (u16)

    f32x4 acc[8];
#pragma unroll
    for (int i = 0; i < 8; ++i) acc[i] = (f32x4){0.f, 0.f, 0.f, 0.f};

    // granule slot for A-frag: f(node, ks, g) = ks*64 + g*16 + (node ^ (ks*4+g))
    auto writeFragQ = [&](int node, uint4 u) {   // lane's cols = mm*8..+7
        int ks = mm >> 2, g = mm & 3;
        int slot = ks * 64 + g * 16 + (node ^ (ks * 4 + g));
        *(uint4*)&fH[wbU + slot * 8] = u;
    };
    auto loadA = [&](bf16x8* AH) {
#pragma unroll
        for (int ks = 0; ks < 4; ++ks) {
            int slot = ks * 64 + qd * 16 + (mm ^ (ks * 4 + qd));
            AH[ks] = *(const bf16x8*)&fH[wbU + slot * 8];
        }
    };

    // stage k-quarter `step` (mat step>>2, cols (step&3)*32..) into sQ[bufi]
    auto stage = [&](int step, int bufi) {
        const u16* src = wtH + (step >> 2) * 16384 + (step & 3) * 32;
#pragma unroll
        for (int i = 0; i < 2; ++i) {            // 512 granules, 2/thread
            int u = i * 256 + tid;
            int n = u >> 2, j = u & 3;
            gl_lds16(src + n * 128 + ((j ^ ((n >> 1) & 3)) * 8), &sQ[bufi][u * 8]);
        }
    };
    auto mfma_quarter = [&](int bufi, bf16x8 A) {
        const u16* buf = sQ[bufi];
#pragma unroll
        for (int nt = 0; nt < 8; ++nt) {
            int n = nt * 16 + mm;
            int slot = n * 4 + (qd ^ ((n >> 1) & 3));
            bf16x8 B = *(const bf16x8*)&buf[slot * 8];
            acc[nt] = __builtin_amdgcn_mfma_f32_16x16x32_bf16(A, B, acc[nt], 0, 0, 0);
        }
    };

    // prefetch relation g's sorted-index range into sIdx[sbuf] (wave-private)
    auto prefetchIdx = [&](int g, int sbuf) {
        int bidx0 = g * NN + row0 + wave * 16;
        int w0 = offs[bidx0];
        int i16 = bidx0 + 16;
        int w1 = (i16 < NRSEG) ? offs[i16] : EE;
        if (lane == 0) { sMeta[sbuf][wave][0] = w0; sMeta[sbuf][wave][1] = w1; }
        int wcnt = w1 - w0;
        if (wcnt > ICAP) wcnt = ICAP;            // fallback handled in gather
        for (int i = lane; i < wcnt; i += 64)
            sIdx[sbuf][wave * ICAP + i] = (int)sorted[w0 + i];
    };

    // mean-aggregate ONE node (t2) of relation g -> fH fragment
    auto gather_node = [&](int g, int sbuf, int t2, int r0, int r1) {
        int w0 = sMeta[sbuf][wave][0];
        int w1 = sMeta[sbuf][wave][1];
        bool fits = (w1 - w0 <= ICAP);
        const int* si = &sIdx[sbuf][wave * ICAP];
        int node = t2 * 4 + qd;
        int o  = r0 - w0;
        int cnt = r1 - r0;
        float ax[8];
#pragma unroll
        for (int i = 0; i < 8; ++i) ax[i] = 0.f;

        auto upk = [&](uint4 u) {
            ax[0] += __uint_as_float(u.x << 16);
            ax[1] += __uint_as_float(u.x & 0xffff0000u);
            ax[2] += __uint_as_float(u.y << 16);
            ax[3] += __uint_as_float(u.y & 0xffff0000u);
            ax[4] += __uint_as_float(u.z << 16);
            ax[5] += __uint_as_float(u.z & 0xffff0000u);
            ax[6] += __uint_as_float(u.w << 16);
            ax[7] += __uint_as_float(u.w & 0xffff0000u);
        };

        int j = 0;
        if (fits) {
            for (; j + 8 <= cnt; j += 8) {       // exact batches: 8 / 4 / 2 / 1
                uint4 v0 = *(const uint4*)&hin[si[o+j+0] * DD + mm * 8];
                uint4 v1 = *(const uint4*)&hin[si[o+j+1] * DD + mm * 8];
                uint4 v2 = *(const uint4*)&hin[si[o+j+2] * DD + mm * 8];
                uint4 v3 = *(const uint4*)&hin[si[o+j+3] * DD + mm * 8];
                uint4 v4 = *(const uint4*)&hin[si[o+j+4] * DD + mm * 8];
                uint4 v5 = *(const uint4*)&hin[si[o+j+5] * DD + mm * 8];
                uint4 v6 = *(const uint4*)&hin[si[o+j+6] * DD + mm * 8];
                uint4 v7 = *(const uint4*)&hin[si[o+j+7] * DD + mm * 8];
                upk(v0); upk(v1); upk(v2); upk(v3);
                upk(v4); upk(v5); upk(v6); upk(v7);
            }
            if (j + 4 <= cnt) {
                uint4 v0 = *(const uint4*)&hin[si[o+j+0] * DD + mm * 8];
                uint4 v1 = *(const uint4*)&hin[si[o+j+1] * DD + mm * 8];
                uint4 v2 = *(const uint4*)&hin[si[o+j+2] * DD + mm * 8];
                uint4 v3 = *(const uint4*)&hin[si[o+j+3] * DD + mm * 8];
                upk(v0); upk(v1); upk(v2); upk(v3);
                j += 4;
            }
            if (j + 2 <= cnt) {
                uint4 v0 = *(const uint4*)&hin[si[o+j+0] * DD + mm * 8];
                uint4 v1 = *(const uint4*)&hin[si[o+j+1] * DD + mm * 8];
                upk(v0); upk(v1);
                j += 2;
            }
            if (j < cnt)
                upk(*(const uint4*)&hin[si[o+j] * DD + mm * 8]);
        } else {
            for (; j + 4 <= cnt; j += 4) {
                uint4 v0 = *(const uint4*)&hin[(int)sorted[r0+j+0] * DD + mm * 8];
                uint4 v1 = *(const uint4*)&hin[(int)sorted[r0+j+1] * DD + mm * 8];
                uint4 v2 = *(const uint4*)&hin[(int)sorted[r0+j+2] * DD + mm * 8];
                uint4 v3 = *(const uint4*)&hin[(int)sorted[r0+j+3] * DD + mm * 8];
                upk(v0); upk(v1); upk(v2); upk(v3);
            }
            if (j + 2 <= cnt) {
                uint4 v0 = *(const uint4*)&hin[(int)sorted[r0+j+0] * DD + mm * 8];
                uint4 v1 = *(const uint4*)&hin[(int)sorted[r0+j+1] * DD + mm * 8];
                upk(v0); upk(v1);
                j += 2;
            }
            if (j < cnt)
                upk(*(const uint4*)&hin[(int)sorted[r0+j] * DD + mm * 8]);
        }
        float s = sInv[wave * 64 + g * 16 + node];
        u32 h0 = bf16_rne(ax[0] * s), h1 = bf16_rne(ax[1] * s);
        u32 h2 = bf16_rne(ax[2] * s), h3 = bf16_rne(ax[3] * s);
        u32 h4 = bf16_rne(ax[4] * s), h5 = bf16_rne(ax[5] * s);
        u32 h6 = bf16_rne(ax[6] * s), h7 = bf16_rne(ax[7] * s);
        uint4 pk;
        pk.x = h0 | (h1 << 16); pk.y = h2 | (h3 << 16);
        pk.z = h4 | (h5 << 16); pk.w = h6 | (h7 << 16);
        writeFragQ(node, pk);
    };

    // ---- prologue ----
    prefetchIdx(0, 0);                           // relation 0 indices
    stage(0, 0);                                 // mat0 quarter0 DMA
    {   // prestage inv for all 4 relations (1 load/lane, wave-private)
        int g = lane >> 4, node = lane & 15;
        sInv[wave * 64 + lane] = inv[g * NN + row0 + wave * 16 + node];
    }
#pragma unroll
    for (int t2 = 0; t2 < 4; ++t2) {             // root A-frags (hin already bf16)
        int node = t2 * 4 + qd;
        uint4 u = *(const uint4*)&hin[(row0 + wave * 16 + node) * DD + mm * 8];
        writeFragQ(node, u);
    }
    __syncthreads();                             // buf0 DMA drained

    // ---- 5 matrices: mat0 = root, mat 1..4 = rel 0..3.
    // During mat m's quarters we also gather relation m (for mat m+1). ----
    for (int m = 0; m < 5; ++m) {
        bf16x8 AH[4];
        loadA(AH);
        int r0v[4], r1v[4];
        if (m < 4) {
            int bidx0 = m * NN + row0 + wave * 16;
#pragma unroll
            for (int t2 = 0; t2 < 4; ++t2) {     // 8 independent offs loads, early
                int b = bidx0 + t2 * 4 + qd;
                r0v[t2] = offs[b];
                r1v[t2] = (b + 1 < NRSEG) ? offs[b + 1] : EE;
            }
            if (m + 1 < 4) prefetchIdx(m + 1, (m + 1) & 1);
        }
#pragma unroll
        for (int q = 0; q < 4; ++q) {
            int step = m * 4 + q;
            if (step + 1 < 20) stage(step + 1, (step + 1) & 1);
            mfma_quarter(step & 1, AH[q]);
            if (m < 4) gather_node(m, m & 1, q, r0v[q], r1v[q]);
            __syncthreads();                     // next buf drained; this buf free
        }
    }

    // ---- epilogue ----
    float bvv[8];
#pragma unroll
    for (int nt = 0; nt < 8; ++nt) bvv[nt] = bias[nt * 16 + mm];

    if constexpr (LAST) {
        int gidx = row0 >> 7;                    // 64-node blocks never straddle graphs
#pragma unroll
        for (int nt = 0; nt < 8; ++nt) {
            float v0 = acc[nt][0], v1 = acc[nt][1], v2 = acc[nt][2], v3 = acc[nt][3];
            float v = fmaxf(fmaxf(v0, v1), fmaxf(v2, v3)) + bvv[nt];
            v = fmaxf(v, 0.f);                   // relu(max) == max(relu) per column
            v = fmaxf(v, __shfl_xor(v, 16));
            v = fmaxf(v, __shfl_xor(v, 32));
            if (lane < 16)
                atomicMax((u32*)&outF[gidx * DD + nt * 16 + mm], __float_as_uint(v));
        }
    } else {
        u16* fs = &fH[wbU];                      // bounce for coalesced bf16 rows
#pragma unroll
        for (int nt = 0; nt < 8; ++nt)
#pragma unroll
            for (int r = 0; r < 4; ++r)
                fs[(qd * 4 + r) * 128 + nt * 16 + mm] =
                    (u16)bf16_rne(fmaxf(acc[nt][r] + bvv[nt], 0.f));
        uint4* dst = (uint4*)&houtH[(row0 + wave * 16) * DD];
        const uint4* src = (const uint4*)fs;
#pragma unroll
        for (int i = 0; i < 4; ++i) dst[i * 64 + lane] = src[i * 64 + lane];
    }
}

// ---------------- launch ----------------

extern "C" void kernel_launch(void* const* d_in, const int* in_sizes, int n_in,
                              void* d_out, int out_size, void* d_ws, size_t ws_size,
                              hipStream_t stream) {
    const float* x      = (const float*)d_in[0];
    const int*   ei     = (const int*)  d_in[1];
    const int*   ea     = (const int*)  d_in[2];
    const float* W_emb  = (const float*)d_in[3];
    const float* b_emb  = (const float*)d_in[4];
    const float* W_root = (const float*)d_in[5];
    const float* W_rel  = (const float*)d_in[6];
    const float* bias   = (const float*)d_in[7];
    float* out = (float*)d_out;

    char* p = (char*)d_ws;
    u16*      h0H    = (u16*)p;      p += (size_t)NN * DD * 2;      // 16.78 MB
    u16*      h1H    = (u16*)p;      p += (size_t)NN * DD * 2;      // 16.78 MB
    u32*      bc     = (u32*)p;      p += 1024;                     // bucket counts
    u32*      bcur   = (u32*)p;      p += 1024;                     // binA cursors
    u32*      bbase  = (u32*)p;      p += 1024;                     // pristine bases
    float*    inv    = (float*)p;    p += (size_t)NRSEG * 4;        // 1 MB
    int*      offs   = (int*)p;      p += (size_t)NRSEG * 4;        // 1 MB
    u32*      binned = (u32*)p;      p += (size_t)EE * 4;           // 6.29 MB
    u16*      sorted = (u16*)p;      p += (size_t)EE * 2;           // 3.15 MB
    u16*      wtH    = (u16*)p;      p += (size_t)10 * 16384 * 2;   // 0.33 MB

    hipMemsetAsync(bc, 0, 1024, stream);

    k_front<<<1920, 256, 0, stream>>>(x, W_emb, b_emb, h0H, ei, ea, bc,
                                      W_root, W_rel, wtH, out);
    k_mini <<<1, 256, 0, stream>>>(bc, bcur, bbase);
    k_binA <<<192, 256, 0, stream>>>(ei, ea, bcur, binned);
    k_binB <<<256, 256, 0, stream>>>(binned, bbase, offs, inv, sorted);

    k_layer<0><<<NN / 64, 256, 0, stream>>>(h0H, h1H, nullptr,
                                            wtH, bias, sorted, offs, inv);
    k_layer<1><<<NN / 64, 256, 0, stream>>>(h1H, nullptr, out,
                                            wtH + 81920, bias + 128,
                                            sorted, offs, inv);
}

// Round 12
// 275.496 us; speedup vs baseline: 1.1982x; 1.1982x over previous
//
#include <hip/hip_runtime.h>

// Problem constants
constexpr int GG    = 512;          // graphs
constexpr int NPG   = 128;          // nodes per graph
constexpr int FIN   = 64;
constexpr int DD    = 128;
constexpr int RR    = 4;
constexpr int NN    = GG * NPG;     // 65536 nodes
constexpr int EE    = 1572864;      // edges
constexpr int NRSEG = NN * RR;      // 262144 segments (key = r*NN + dst)
constexpr int BCAP  = 7680;         // per-bucket capacity in k_binB (avg 6144, sd ~78)

typedef __attribute__((ext_vector_type(8))) short bf16x8;
typedef __attribute__((ext_vector_type(4))) float f32x4;
typedef unsigned short u16;
typedef unsigned int   u32;

__device__ __forceinline__ u32 bf16_rne(float x) {
    u32 u = __float_as_uint(x);
    return (u + 0x7FFFu + ((u >> 16) & 1u)) >> 16;
}

// async global->LDS DMA, 16 B per lane; LDS side must be uniform-base + lane*16
__device__ __forceinline__ void gl_lds16(const void* g, void* l) {
    __builtin_amdgcn_global_load_lds((const __attribute__((address_space(1))) u32*)g,
                                     (__attribute__((address_space(3))) u32*)l, 16, 0, 0);
}

// ---------------- fused front: embed + bucket-count + prep + out-zero --------
// blocks [0,1024): embed | [1024,1216): bucket-count | [1216,1856): prep |
// [1856,1920): zero out. NOTE: zero-out covers ALL GG*DD floats — harness
// re-poisons d_out to 0xAA each replay; atomicMax keeps poison otherwise.

__global__ __launch_bounds__(256, 2) void k_front(const float* __restrict__ x,
                                                  const float* __restrict__ W_emb,
                                                  const float* __restrict__ b_emb,
                                                  u16* __restrict__ h,
                                                  const int* __restrict__ ei,
                                                  const int* __restrict__ ea,
                                                  u32* __restrict__ bc,
                                                  const float* __restrict__ W_root,
                                                  const float* __restrict__ W_rel,
                                                  u16* __restrict__ wtH,
                                                  float* __restrict__ outF) {
    __shared__ float sA[16 * 64];
    __shared__ float sB[16 * 128];
    __shared__ int bh[256];
    int tid = threadIdx.x;
    int bid = blockIdx.x;

    if (bid < 1024) {
        // ---- embed: h = bf16(x @ W_emb + b_emb) ----
        int tx = tid & 31, ty = tid >> 5;
        int row0 = bid * 64;
        float4 bv = *(const float4*)&b_emb[tx * 4];
        float acc[8][4];
#pragma unroll
        for (int i = 0; i < 8; ++i) { acc[i][0]=bv.x; acc[i][1]=bv.y; acc[i][2]=bv.z; acc[i][3]=bv.w; }
        for (int kb = 0; kb < 4; ++kb) {
            {
                int rr = tid >> 2, kq = tid & 3;
                float4 v = *(const float4*)&x[(row0 + rr) * FIN + kb * 16 + kq * 4];
                sA[(kq*4+0)*64 + rr] = v.x;
                sA[(kq*4+1)*64 + rr] = v.y;
                sA[(kq*4+2)*64 + rr] = v.z;
                sA[(kq*4+3)*64 + rr] = v.w;
            }
#pragma unroll
            for (int i = 0; i < 2; ++i) {
                int f = tid + i * 256;
                *(float4*)&sB[f * 4] = *(const float4*)&W_emb[kb * 16 * 128 + f * 4];
            }
            __syncthreads();
#pragma unroll
            for (int kk = 0; kk < 16; ++kk) {
                float4 a0 = *(const float4*)&sA[kk * 64 + ty * 4];
                float4 a1 = *(const float4*)&sA[kk * 64 + 32 + ty * 4];
                float4 bq = *(const float4*)&sB[kk * 128 + tx * 4];
                float ar[8] = {a0.x,a0.y,a0.z,a0.w,a1.x,a1.y,a1.z,a1.w};
#pragma unroll
                for (int i = 0; i < 8; ++i) {
                    acc[i][0] = fmaf(ar[i], bq.x, acc[i][0]);
                    acc[i][1] = fmaf(ar[i], bq.y, acc[i][1]);
                    acc[i][2] = fmaf(ar[i], bq.z, acc[i][2]);
                    acc[i][3] = fmaf(ar[i], bq.w, acc[i][3]);
                }
            }
            __syncthreads();
        }
#pragma unroll
        for (int i = 0; i < 8; ++i) {
            int row = (i < 4) ? (ty * 4 + i) : (32 + ty * 4 + (i - 4));
            u32 s0 = bf16_rne(acc[i][0]), s1 = bf16_rne(acc[i][1]);
            u32 s2 = bf16_rne(acc[i][2]), s3 = bf16_rne(acc[i][3]);
            *(uint2*)&h[(row0 + row) * DD + tx * 4] = make_uint2(s0 | (s1 << 16), s2 | (s3 << 16));
        }
    } else if (bid < 1216) {
        // ---- bucket-count: LDS hist of bucket = (a<<6)|(dst>>10) ----
        int e0 = (bid - 1024) * 8192;          // 192 blocks cover EE exactly
        bh[tid] = 0;
        __syncthreads();
        for (int i = 0; i < 32; ++i) {
            int e = e0 + i * 256 + tid;
            int dst = ei[EE + e];
            int a   = ea[e];
            atomicAdd(&bh[(a << 6) | (dst >> 10)], 1);
        }
        __syncthreads();
        atomicAdd(&bc[tid], (u32)bh[tid]);
    } else if (bid < 1856) {
        // ---- prep: transpose weights to bf16, wt[mat*16384 + n*128 + k] ----
        int idx = (bid - 1216) * 256 + tid;    // covers 10*16384
        int mat = idx >> 14;
        int rem = idx & 16383;
        int n = rem >> 7, k = rem & 127;
        int l = mat / 5, m5 = mat - l * 5;
        float v = (m5 == 0) ? W_root[l * 16384 + k * 128 + n]
                            : W_rel[((l * RR + (m5 - 1)) * 128 + k) * 128 + n];
        wtH[idx] = (u16)bf16_rne(v);
    } else {
        // ---- zero out (fused maxpool init; relu >= 0): float4 covers GG*DD ----
        int i = (bid - 1856) * 256 + tid;      // 16384 threads x 4 floats = 65536
        *(float4*)&outF[i * 4] = make_float4(0.f, 0.f, 0.f, 0.f);
    }
}

// ---------------- tiny scan: 256 bucket totals -> bases ----------------------

__global__ __launch_bounds__(256) void k_mini(const u32* __restrict__ bc,
                                              u32* __restrict__ bcur,
                                              u32* __restrict__ bbase) {
    __shared__ int ts[256];
    int tid = threadIdx.x;
    int v = (int)bc[tid];
    ts[tid] = v;
    __syncthreads();
    for (int o = 1; o < 256; o <<= 1) {
        int t = (tid >= o) ? ts[tid - o] : 0;
        __syncthreads();
        ts[tid] += t;
        __syncthreads();
    }
    u32 ex = (u32)(ts[tid] - v);
    bcur[tid]  = ex;
    bbase[tid] = ex;
}

// ---------------- bucketed scatter phase A: bin edges by bucket --------------
// Block owns 8192 edges; LDS histogram, one global atomic per (block,bucket)
// reserves a contiguous run in binned -> line-local writes.

__global__ __launch_bounds__(256) void k_binA(const int* __restrict__ ei,
                                              const int* __restrict__ ea,
                                              u32* __restrict__ bcur,
                                              u32* __restrict__ binned) {
    __shared__ int bh[256];
    __shared__ int lcur[256];
    int tid = threadIdx.x;
    int e0 = blockIdx.x * 8192;                // 192 blocks cover EE exactly
    bh[tid] = 0;
    __syncthreads();
    for (int i = 0; i < 32; ++i) {
        int e = e0 + i * 256 + tid;
        int dst = ei[EE + e];
        int a   = ea[e];
        atomicAdd(&bh[(a << 6) | (dst >> 10)], 1);
    }
    __syncthreads();
    lcur[tid] = (int)atomicAdd(&bcur[tid], (u32)bh[tid]);
    __syncthreads();
    for (int i = 0; i < 32; ++i) {
        int e = e0 + i * 256 + tid;
        int src = ei[e];
        int dst = ei[EE + e];
        int a   = ea[e];
        int pos = atomicAdd(&lcur[(a << 6) | (dst >> 10)], 1);
        binned[pos] = (u32)src | ((u32)dst << 16);
    }
}

// ---------------- bucketed scatter phase B: sort + emit offs/inv -------------
// One block per bucket. Subkey = dst&1023. LDS count + prefix -> writes the
// 1024 segment offsets (offs) and inverse counts (inv) for its key range,
// then rank-scatters srcs (u16) via LDS staging (contiguous flush).

__global__ __launch_bounds__(256) void k_binB(const u32* __restrict__ binned,
                                              const u32* __restrict__ bbase,
                                              int* __restrict__ offs,
                                              float* __restrict__ inv,
                                              u16* __restrict__ sorted) {
    __shared__ int pc[1024];
    __shared__ int ts[256];
    __shared__ u16 stg[BCAP];
    int tid = threadIdx.x;
    int b = blockIdx.x;
    int p0 = (int)bbase[b];
    int p1 = (b == 255) ? EE : (int)bbase[b + 1];
    int cnt = p1 - p0;
    bool fits = (cnt <= BCAP);

#pragma unroll
    for (int i = 0; i < 4; ++i) pc[i * 256 + tid] = 0;
    __syncthreads();
    for (int i = tid; i < cnt; i += 256) {
        u32 rec = binned[p0 + i];
        atomicAdd(&pc[(rec >> 16) & 1023], 1);
    }
    __syncthreads();
    int v[4], s = 0;
#pragma unroll
    for (int i = 0; i < 4; ++i) { v[i] = pc[tid * 4 + i]; s += v[i]; }
    ts[tid] = s;
    __syncthreads();
    for (int o = 1; o < 256; o <<= 1) {
        int t = (tid >= o) ? ts[tid - o] : 0;
        __syncthreads();
        ts[tid] += t;
        __syncthreads();
    }
    int ex = ts[tid] - s;
    // emit offs + inv for this thread's 4 keys, and store local prefix in pc
    {
        int4 o4; float4 i4;
        int e = ex;
#pragma unroll
        for (int i = 0; i < 4; ++i) {
            (&o4.x)[i] = p0 + e;
            (&i4.x)[i] = 1.0f / (float)(v[i] > 0 ? v[i] : 1);
            e += v[i];
        }
        *(int4*)&offs[(b << 10) + tid * 4]  = o4;
        *(float4*)&inv[(b << 10) + tid * 4] = i4;
    }
    __syncthreads();                            // counts consumed
#pragma unroll
    for (int i = 0; i < 4; ++i) { pc[tid * 4 + i] = ex; ex += v[i]; }
    __syncthreads();
    if (fits) {
        for (int i = tid; i < cnt; i += 256) {
            u32 rec = binned[p0 + i];
            int pos = atomicAdd(&pc[(rec >> 16) & 1023], 1);
            stg[pos] = (u16)(rec & 0xFFFFu);
        }
        __syncthreads();
        for (int i = tid; i < cnt; i += 256) sorted[p0 + i] = stg[i];
    } else {
        for (int i = tid; i < cnt; i += 256) {
            u32 rec = binned[p0 + i];
            int pos = atomicAdd(&pc[(rec >> 16) & 1023], 1);
            sorted[p0 + pos] = (u16)(rec & 0xFFFFu);
        }
    }
}

// ---------------- fused RGCN layer ----------------
// 256 threads = 4 waves; wave owns a 16-node M-strip.
// Round-10 structure (phase gather AFTER each mat's quarters — folding gather
// into the quarter loop regressed: FETCH 30->107 MB, L2 reuse window blown).
// Gather: quarter-wave (16 lanes/node, uint4, 4 chains in flight) with exact
// 8/4/2/1 batches (Poisson(6) sizes: serial tail was the dominant latency).
// sIdx dbuf prefetch one relation ahead; inv prestaged; offs hoisted.
// LDS: fH 16K + sQ 16K + sIdx 6K + sInv 1K + sMeta = 40000 B -> 4 blocks/CU.

constexpr int ICAP = 192;   // per-wave sIdx capacity (wcnt avg 96, sd ~10)

template<int LAST>
__global__ __launch_bounds__(256, 4) void k_layer(const u16* __restrict__ hin,
                                                  u16* __restrict__ houtH,
                                                  float* __restrict__ outF,
                                                  const u16* __restrict__ wtH,
                                                  const float* __restrict__ bias,
                                                  const u16* __restrict__ sorted,
                                                  const int* __restrict__ offs,
                                                  const float* __restrict__ inv) {
    __shared__ __align__(16) u16 fH[4 * 2048];   // 16 KB A-frags (swizzled, wave-private)
    __shared__ __align__(16) u16 sQ[2][4096];    // 2 x 8 KB B k-quarter buffers
    __shared__ int   sIdx[2][4 * ICAP];          // 6 KB dbuf gather indices
    __shared__ float sInv[4 * 64];               // 1 KB prestaged inverse counts
    __shared__ int   sMeta[2][4][2];             // (w0, w1) per buf/wave

    int tid  = threadIdx.x;
    int wave = tid >> 6, lane = tid & 63;
    int mm   = lane & 15;            // MFMA m/n lane; gather col-octet
    int qd   = lane >> 4;            // MFMA quad; gather quarter (node group)
    int row0 = blockIdx.x * 64;
    int wbU  = wave * 2048;          // fH wave base (u16)

    f32x4 acc[8];
#pragma unroll
    for (int i = 0; i < 8; ++i) acc[i] = (f32x4){0.f, 0.f, 0.f, 0.f};

    // granule slot for A-frag: f(node, ks, g) = ks*64 + g*16 + (node ^ (ks*4+g))
    auto writeFragQ = [&](int node, uint4 u) {   // lane's cols = mm*8..+7
        int ks = mm >> 2, g = mm & 3;
        int slot = ks * 64 + g * 16 + (node ^ (ks * 4 + g));
        *(uint4*)&fH[wbU + slot * 8] = u;
    };
    auto loadA = [&](bf16x8* AH) {
#pragma unroll
        for (int ks = 0; ks < 4; ++ks) {
            int slot = ks * 64 + qd * 16 + (mm ^ (ks * 4 + qd));
            AH[ks] = *(const bf16x8*)&fH[wbU + slot * 8];
        }
    };

    // stage k-quarter `step` (mat step>>2, cols (step&3)*32..) into sQ[bufi]
    auto stage = [&](int step, int bufi) {
        const u16* src = wtH + (step >> 2) * 16384 + (step & 3) * 32;
#pragma unroll
        for (int i = 0; i < 2; ++i) {            // 512 granules, 2/thread
            int u = i * 256 + tid;
            int n = u >> 2, j = u & 3;
            gl_lds16(src + n * 128 + ((j ^ ((n >> 1) & 3)) * 8), &sQ[bufi][u * 8]);
        }
    };
    auto mfma_quarter = [&](int bufi, bf16x8 A) {
        const u16* buf = sQ[bufi];
#pragma unroll
        for (int nt = 0; nt < 8; ++nt) {
            int n = nt * 16 + mm;
            int slot = n * 4 + (qd ^ ((n >> 1) & 3));
            bf16x8 B = *(const bf16x8*)&buf[slot * 8];
            acc[nt] = __builtin_amdgcn_mfma_f32_16x16x32_bf16(A, B, acc[nt], 0, 0, 0);
        }
    };

    // prefetch relation g's sorted-index range into sIdx[sbuf] (wave-private)
    auto prefetchIdx = [&](int g, int sbuf) {
        int bidx0 = g * NN + row0 + wave * 16;
        int w0 = offs[bidx0];
        int i16 = bidx0 + 16;
        int w1 = (i16 < NRSEG) ? offs[i16] : EE;
        if (lane == 0) { sMeta[sbuf][wave][0] = w0; sMeta[sbuf][wave][1] = w1; }
        int wcnt = w1 - w0;
        if (wcnt > ICAP) wcnt = ICAP;            // fallback handled in gather
        for (int i = lane; i < wcnt; i += 64)
            sIdx[sbuf][wave * ICAP + i] = (int)sorted[w0 + i];
    };

    // per-relation mean-aggregate, quarter-wave: 4 nodes in flight
    auto gather = [&](int g, int sbuf) {
        int bidx0 = g * NN + row0 + wave * 16;
        int w0 = sMeta[sbuf][wave][0];
        int w1 = sMeta[sbuf][wave][1];
        bool fits = (w1 - w0 <= ICAP);
        const int* si = &sIdx[sbuf][wave * ICAP];

        // hoist all 8 offs loads (independent; issue together)
        int r0v[4], r1v[4];
#pragma unroll
        for (int t2 = 0; t2 < 4; ++t2) {
            int b = bidx0 + t2 * 4 + qd;
            r0v[t2] = offs[b];
            r1v[t2] = (b + 1 < NRSEG) ? offs[b + 1] : EE;
        }

#pragma unroll
        for (int t2 = 0; t2 < 4; ++t2) {
            int node = t2 * 4 + qd;
            int r0 = r0v[t2], r1 = r1v[t2];
            int o  = r0 - w0;
            int cnt = r1 - r0;
            float ax[8];
#pragma unroll
            for (int i = 0; i < 8; ++i) ax[i] = 0.f;

            auto upk = [&](uint4 u) {
                ax[0] += __uint_as_float(u.x << 16);
                ax[1] += __uint_as_float(u.x & 0xffff0000u);
                ax[2] += __uint_as_float(u.y << 16);
                ax[3] += __uint_as_float(u.y & 0xffff0000u);
                ax[4] += __uint_as_float(u.z << 16);
                ax[5] += __uint_as_float(u.z & 0xffff0000u);
                ax[6] += __uint_as_float(u.w << 16);
                ax[7] += __uint_as_float(u.w & 0xffff0000u);
            };

            int j = 0;
            if (fits) {
                for (; j + 8 <= cnt; j += 8) {   // exact batches: 8 / 4 / 2 / 1
                    uint4 v0 = *(const uint4*)&hin[si[o+j+0] * DD + mm * 8];
                    uint4 v1 = *(const uint4*)&hin[si[o+j+1] * DD + mm * 8];
                    uint4 v2 = *(const uint4*)&hin[si[o+j+2] * DD + mm * 8];
                    uint4 v3 = *(const uint4*)&hin[si[o+j+3] * DD + mm * 8];
                    uint4 v4 = *(const uint4*)&hin[si[o+j+4] * DD + mm * 8];
                    uint4 v5 = *(const uint4*)&hin[si[o+j+5] * DD + mm * 8];
                    uint4 v6 = *(const uint4*)&hin[si[o+j+6] * DD + mm * 8];
                    uint4 v7 = *(const uint4*)&hin[si[o+j+7] * DD + mm * 8];
                    upk(v0); upk(v1); upk(v2); upk(v3);
                    upk(v4); upk(v5); upk(v6); upk(v7);
                }
                if (j + 4 <= cnt) {
                    uint4 v0 = *(const uint4*)&hin[si[o+j+0] * DD + mm * 8];
                    uint4 v1 = *(const uint4*)&hin[si[o+j+1] * DD + mm * 8];
                    uint4 v2 = *(const uint4*)&hin[si[o+j+2] * DD + mm * 8];
                    uint4 v3 = *(const uint4*)&hin[si[o+j+3] * DD + mm * 8];
                    upk(v0); upk(v1); upk(v2); upk(v3);
                    j += 4;
                }
                if (j + 2 <= cnt) {
                    uint4 v0 = *(const uint4*)&hin[si[o+j+0] * DD + mm * 8];
                    uint4 v1 = *(const uint4*)&hin[si[o+j+1] * DD + mm * 8];
                    upk(v0); upk(v1);
                    j += 2;
                }
                if (j < cnt)
                    upk(*(const uint4*)&hin[si[o+j] * DD + mm * 8]);
            } else {
                for (; j + 4 <= cnt; j += 4) {
                    uint4 v0 = *(const uint4*)&hin[(int)sorted[r0+j+0] * DD + mm * 8];
                    uint4 v1 = *(const uint4*)&hin[(int)sorted[r0+j+1] * DD + mm * 8];
                    uint4 v2 = *(const uint4*)&hin[(int)sorted[r0+j+2] * DD + mm * 8];
                    uint4 v3 = *(const uint4*)&hin[(int)sorted[r0+j+3] * DD + mm * 8];
                    upk(v0); upk(v1); upk(v2); upk(v3);
                }
                if (j + 2 <= cnt) {
                    uint4 v0 = *(const uint4*)&hin[(int)sorted[r0+j+0] * DD + mm * 8];
                    uint4 v1 = *(const uint4*)&hin[(int)sorted[r0+j+1] * DD + mm * 8];
                    upk(v0); upk(v1);
                    j += 2;
                }
                if (j < cnt)
                    upk(*(const uint4*)&hin[(int)sorted[r0+j] * DD + mm * 8]);
            }
            float s = sInv[wave * 64 + g * 16 + node];
            u32 h0 = bf16_rne(ax[0] * s), h1 = bf16_rne(ax[1] * s);
            u32 h2 = bf16_rne(ax[2] * s), h3 = bf16_rne(ax[3] * s);
            u32 h4 = bf16_rne(ax[4] * s), h5 = bf16_rne(ax[5] * s);
            u32 h6 = bf16_rne(ax[6] * s), h7 = bf16_rne(ax[7] * s);
            uint4 pk;
            pk.x = h0 | (h1 << 16); pk.y = h2 | (h3 << 16);
            pk.z = h4 | (h5 << 16); pk.w = h6 | (h7 << 16);
            writeFragQ(node, pk);
        }
    };

    // ---- prologue ----
    prefetchIdx(0, 0);                           // relation 0 indices
    stage(0, 0);                                 // mat0 quarter0 DMA
    {   // prestage inv for all 4 relations (1 load/lane, wave-private)
        int g = lane >> 4, node = lane & 15;
        sInv[wave * 64 + lane] = inv[g * NN + row0 + wave * 16 + node];
    }
#pragma unroll
    for (int t2 = 0; t2 < 4; ++t2) {             // root A-frags (hin already bf16)
        int node = t2 * 4 + qd;
        uint4 u = *(const uint4*)&hin[(row0 + wave * 16 + node) * DD + mm * 8];
        writeFragQ(node, u);
    }
    __syncthreads();                             // buf0 DMA drained

    // ---- 5 matrices: mat0 = root, mat 1..4 = rel 0..3 ----
    for (int m = 0; m < 5; ++m) {
        bf16x8 AH[4];
        loadA(AH);
#pragma unroll
        for (int q = 0; q < 4; ++q) {
            int step = m * 4 + q;
            if (step + 1 < 20) stage(step + 1, (step + 1) & 1);
            mfma_quarter(step & 1, AH[q]);
            __syncthreads();                     // next buf drained; this buf free
        }
        if (m < 4) {
            if (m + 1 < 4) prefetchIdx(m + 1, (m + 1) & 1);  // hide idx latency
            gather(m, m & 1);                    // refill fH (wave-private; AH dead)
        }
    }

    // ---- epilogue ----
    float bvv[8];
#pragma unroll
    for (int nt = 0; nt < 8; ++nt) bvv[nt] = bias[nt * 16 + mm];

    if constexpr (LAST) {
        int gidx = row0 >> 7;                    // 64-node blocks never straddle graphs
#pragma unroll
        for (int nt = 0; nt < 8; ++nt) {
            float v0 = acc[nt][0], v1 = acc[nt][1], v2 = acc[nt][2], v3 = acc[nt][3];
            float v = fmaxf(fmaxf(v0, v1), fmaxf(v2, v3)) + bvv[nt];
            v = fmaxf(v, 0.f);                   // relu(max) == max(relu) per column
            v = fmaxf(v, __shfl_xor(v, 16));
            v = fmaxf(v, __shfl_xor(v, 32));
            if (lane < 16)
                atomicMax((u32*)&outF[gidx * DD + nt * 16 + mm], __float_as_uint(v));
        }
    } else {
        u16* fs = &fH[wbU];                      // bounce for coalesced bf16 rows
#pragma unroll
        for (int nt = 0; nt < 8; ++nt)
#pragma unroll
            for (int r = 0; r < 4; ++r)
                fs[(qd * 4 + r) * 128 + nt * 16 + mm] =
                    (u16)bf16_rne(fmaxf(acc[nt][r] + bvv[nt], 0.f));
        uint4* dst = (uint4*)&houtH[(row0 + wave * 16) * DD];
        const uint4* src = (const uint4*)fs;
#pragma unroll
        for (int i = 0; i < 4; ++i) dst[i * 64 + lane] = src[i * 64 + lane];
    }
}

// ---------------- launch ----------------

extern "C" void kernel_launch(void* const* d_in, const int* in_sizes, int n_in,
                              void* d_out, int out_size, void* d_ws, size_t ws_size,
                              hipStream_t stream) {
    const float* x      = (const float*)d_in[0];
    const int*   ei     = (const int*)  d_in[1];
    const int*   ea     = (const int*)  d_in[2];
    const float* W_emb  = (const float*)d_in[3];
    const float* b_emb  = (const float*)d_in[4];
    const float* W_root = (const float*)d_in[5];
    const float* W_rel  = (const float*)d_in[6];
    const float* bias   = (const float*)d_in[7];
    float* out = (float*)d_out;

    char* p = (char*)d_ws;
    u16*      h0H    = (u16*)p;      p += (size_t)NN * DD * 2;      // 16.78 MB
    u16*      h1H    = (u16*)p;      p += (size_t)NN * DD * 2;      // 16.78 MB
    u32*      bc     = (u32*)p;      p += 1024;                     // bucket counts
    u32*      bcur   = (u32*)p;      p += 1024;                     // binA cursors
    u32*      bbase  = (u32*)p;      p += 1024;                     // pristine bases
    float*    inv    = (float*)p;    p += (size_t)NRSEG * 4;        // 1 MB
    int*      offs   = (int*)p;      p += (size_t)NRSEG * 4;        // 1 MB
    u32*      binned = (u32*)p;      p += (size_t)EE * 4;           // 6.29 MB
    u16*      sorted = (u16*)p;      p += (size_t)EE * 2;           // 3.15 MB
    u16*      wtH    = (u16*)p;      p += (size_t)10 * 16384 * 2;   // 0.33 MB

    hipMemsetAsync(bc, 0, 1024, stream);

    k_front<<<1920, 256, 0, stream>>>(x, W_emb, b_emb, h0H, ei, ea, bc,
                                      W_root, W_rel, wtH, out);
    k_mini <<<1, 256, 0, stream>>>(bc, bcur, bbase);
    k_binA <<<192, 256, 0, stream>>>(ei, ea, bcur, binned);
    k_binB <<<256, 256, 0, stream>>>(binned, bbase, offs, inv, sorted);

    k_layer<0><<<NN / 64, 256, 0, stream>>>(h0H, h1H, nullptr,
                                            wtH, bias, sorted, offs, inv);
    k_layer<1><<<NN / 64, 256, 0, stream>>>(h1H, nullptr, out,
                                            wtH + 81920, bias + 128,
                                            sorted, offs, inv);
}

// Round 13
// 269.483 us; speedup vs baseline: 1.2250x; 1.0223x over previous
//
#include <hip/hip_runtime.h>

// Problem constants
constexpr int GG    = 512;          // graphs
constexpr int NPG   = 128;          // nodes per graph
constexpr int FIN   = 64;
constexpr int DD    = 128;
constexpr int RR    = 4;
constexpr int NN    = GG * NPG;     // 65536 nodes
constexpr int EE    = 1572864;      // edges
constexpr int NRSEG = NN * RR;      // 262144 segments (key = r*NN + dst)
constexpr int BSZ   = 8192;         // static bucket slice (avg fill 6144, sd ~78)
constexpr int BCAP  = 7680;         // LDS staging capacity in k_binB

typedef __attribute__((ext_vector_type(8))) short bf16x8;
typedef __attribute__((ext_vector_type(4))) float f32x4;
typedef unsigned short u16;
typedef unsigned int   u32;

__device__ __forceinline__ u32 bf16_rne(float x) {
    u32 u = __float_as_uint(x);
    return (u + 0x7FFFu + ((u >> 16) & 1u)) >> 16;
}

// async global->LDS DMA, 16 B per lane; LDS side must be uniform-base + lane*16
__device__ __forceinline__ void gl_lds16(const void* g, void* l) {
    __builtin_amdgcn_global_load_lds((const __attribute__((address_space(1))) u32*)g,
                                     (__attribute__((address_space(3))) u32*)l, 16, 0, 0);
}

// ---------------- fused front: embed + binA + prep + out-zero ----------------
// blocks [0,1024): embed | [1024,1216): binA (bucketed edge binning) |
// [1216,1856): prep | [1856,1920): zero out.
// Static bucket slices: bucket b owns binned[b*8192 .. +8192); bcur holds
// bucket-RELATIVE cursors (memset-0 init -> no count pre-pass, no scan).
// NOTE: zero-out covers ALL GG*DD floats — harness re-poisons d_out to 0xAA
// each replay; uint-punned atomicMax would keep poison otherwise.

__global__ __launch_bounds__(256, 2) void k_front(const float* __restrict__ x,
                                                  const float* __restrict__ W_emb,
                                                  const float* __restrict__ b_emb,
                                                  u16* __restrict__ h,
                                                  const int* __restrict__ ei,
                                                  const int* __restrict__ ea,
                                                  u32* __restrict__ bcur,
                                                  u32* __restrict__ binned,
                                                  const float* __restrict__ W_root,
                                                  const float* __restrict__ W_rel,
                                                  u16* __restrict__ wtH,
                                                  float* __restrict__ outF) {
    __shared__ float sA[16 * 64];
    __shared__ float sB[16 * 128];
    __shared__ int bh[256];
    __shared__ int lcur[256];
    int tid = threadIdx.x;
    int bid = blockIdx.x;

    if (bid < 1024) {
        // ---- embed: h = bf16(x @ W_emb + b_emb) ----
        int tx = tid & 31, ty = tid >> 5;
        int row0 = bid * 64;
        float4 bv = *(const float4*)&b_emb[tx * 4];
        float acc[8][4];
#pragma unroll
        for (int i = 0; i < 8; ++i) { acc[i][0]=bv.x; acc[i][1]=bv.y; acc[i][2]=bv.z; acc[i][3]=bv.w; }
        for (int kb = 0; kb < 4; ++kb) {
            {
                int rr = tid >> 2, kq = tid & 3;
                float4 v = *(const float4*)&x[(row0 + rr) * FIN + kb * 16 + kq * 4];
                sA[(kq*4+0)*64 + rr] = v.x;
                sA[(kq*4+1)*64 + rr] = v.y;
                sA[(kq*4+2)*64 + rr] = v.z;
                sA[(kq*4+3)*64 + rr] = v.w;
            }
#pragma unroll
            for (int i = 0; i < 2; ++i) {
                int f = tid + i * 256;
                *(float4*)&sB[f * 4] = *(const float4*)&W_emb[kb * 16 * 128 + f * 4];
            }
            __syncthreads();
#pragma unroll
            for (int kk = 0; kk < 16; ++kk) {
                float4 a0 = *(const float4*)&sA[kk * 64 + ty * 4];
                float4 a1 = *(const float4*)&sA[kk * 64 + 32 + ty * 4];
                float4 bq = *(const float4*)&sB[kk * 128 + tx * 4];
                float ar[8] = {a0.x,a0.y,a0.z,a0.w,a1.x,a1.y,a1.z,a1.w};
#pragma unroll
                for (int i = 0; i < 8; ++i) {
                    acc[i][0] = fmaf(ar[i], bq.x, acc[i][0]);
                    acc[i][1] = fmaf(ar[i], bq.y, acc[i][1]);
                    acc[i][2] = fmaf(ar[i], bq.z, acc[i][2]);
                    acc[i][3] = fmaf(ar[i], bq.w, acc[i][3]);
                }
            }
            __syncthreads();
        }
#pragma unroll
        for (int i = 0; i < 8; ++i) {
            int row = (i < 4) ? (ty * 4 + i) : (32 + ty * 4 + (i - 4));
            u32 s0 = bf16_rne(acc[i][0]), s1 = bf16_rne(acc[i][1]);
            u32 s2 = bf16_rne(acc[i][2]), s3 = bf16_rne(acc[i][3]);
            *(uint2*)&h[(row0 + row) * DD + tx * 4] = make_uint2(s0 | (s1 << 16), s2 | (s3 << 16));
        }
    } else if (bid < 1216) {
        // ---- binA: LDS histogram -> per-(block,bucket) run reservation ----
        int e0 = (bid - 1024) * 8192;          // 192 blocks cover EE exactly
        bh[tid] = 0;
        __syncthreads();
        for (int i = 0; i < 32; ++i) {
            int e = e0 + i * 256 + tid;
            int dst = ei[EE + e];
            int a   = ea[e];
            atomicAdd(&bh[(a << 6) | (dst >> 10)], 1);
        }
        __syncthreads();
        lcur[tid] = tid * BSZ + (int)atomicAdd(&bcur[tid], (u32)bh[tid]);
        __syncthreads();
        for (int i = 0; i < 32; ++i) {
            int e = e0 + i * 256 + tid;
            int src = ei[e];
            int dst = ei[EE + e];
            int a   = ea[e];
            int pos = atomicAdd(&lcur[(a << 6) | (dst >> 10)], 1);
            binned[pos] = (u32)src | ((u32)dst << 16);
        }
    } else if (bid < 1856) {
        // ---- prep: transpose weights to bf16, wt[mat*16384 + n*128 + k] ----
        int idx = (bid - 1216) * 256 + tid;    // covers 10*16384
        int mat = idx >> 14;
        int rem = idx & 16383;
        int n = rem >> 7, k = rem & 127;
        int l = mat / 5, m5 = mat - l * 5;
        float v = (m5 == 0) ? W_root[l * 16384 + k * 128 + n]
                            : W_rel[((l * RR + (m5 - 1)) * 128 + k) * 128 + n];
        wtH[idx] = (u16)bf16_rne(v);
    } else {
        // ---- zero out (fused maxpool init; relu >= 0): float4 covers GG*DD ----
        int i = (bid - 1856) * 256 + tid;      // 16384 threads x 4 floats = 65536
        *(float4*)&outF[i * 4] = make_float4(0.f, 0.f, 0.f, 0.f);
    }
}

// ---------------- binB: within-bucket sort + emit offs/inv/bend --------------
// One block per bucket (static slice [b*8192, +cnt)). Subkey = dst&1023.
// LDS count + prefix -> offs/inv for the bucket's 1024 keys + bend[b] =
// end-of-bucket sentinel (offs[key+1] is invalid across bucket boundaries).
// Then rank-scatter srcs (u16) via LDS staging (contiguous flush).

__global__ __launch_bounds__(256) void k_binB(const u32* __restrict__ binned,
                                              const u32* __restrict__ bcur,
                                              int* __restrict__ offs,
                                              float* __restrict__ inv,
                                              u16* __restrict__ sorted,
                                              int* __restrict__ bend) {
    __shared__ int pc[1024];
    __shared__ int ts[256];
    __shared__ u16 stg[BCAP];
    int tid = threadIdx.x;
    int b = blockIdx.x;
    int p0 = b * BSZ;
    int cnt = (int)bcur[b];
    if (cnt > BSZ) cnt = BSZ;                  // never in practice (26 sigma)
    bool fits = (cnt <= BCAP);
    if (tid == 0) bend[b] = p0 + cnt;

#pragma unroll
    for (int i = 0; i < 4; ++i) pc[i * 256 + tid] = 0;
    __syncthreads();
    for (int i = tid; i < cnt; i += 256) {
        u32 rec = binned[p0 + i];
        atomicAdd(&pc[(rec >> 16) & 1023], 1);
    }
    __syncthreads();
    int v[4], s = 0;
#pragma unroll
    for (int i = 0; i < 4; ++i) { v[i] = pc[tid * 4 + i]; s += v[i]; }
    ts[tid] = s;
    __syncthreads();
    for (int o = 1; o < 256; o <<= 1) {
        int t = (tid >= o) ? ts[tid - o] : 0;
        __syncthreads();
        ts[tid] += t;
        __syncthreads();
    }
    int ex = ts[tid] - s;
    // emit offs + inv for this thread's 4 keys
    {
        int4 o4; float4 i4;
        int e = ex;
#pragma unroll
        for (int i = 0; i < 4; ++i) {
            (&o4.x)[i] = p0 + e;
            (&i4.x)[i] = 1.0f / (float)(v[i] > 0 ? v[i] : 1);
            e += v[i];
        }
        *(int4*)&offs[(b << 10) + tid * 4]  = o4;
        *(float4*)&inv[(b << 10) + tid * 4] = i4;
    }
    __syncthreads();                            // counts consumed
#pragma unroll
    for (int i = 0; i < 4; ++i) { pc[tid * 4 + i] = ex; ex += v[i]; }
    __syncthreads();
    if (fits) {
        for (int i = tid; i < cnt; i += 256) {
            u32 rec = binned[p0 + i];
            int pos = atomicAdd(&pc[(rec >> 16) & 1023], 1);
            stg[pos] = (u16)(rec & 0xFFFFu);
        }
        __syncthreads();
        for (int i = tid; i < cnt; i += 256) sorted[p0 + i] = stg[i];
    } else {
        for (int i = tid; i < cnt; i += 256) {
            u32 rec = binned[p0 + i];
            int pos = atomicAdd(&pc[(rec >> 16) & 1023], 1);
            sorted[p0 + pos] = (u16)(rec & 0xFFFFu);
        }
    }
}

// ---------------- fused RGCN layer ----------------
// 256 threads = 4 waves; wave owns a 16-node M-strip.
// Phase gather AFTER each mat's quarters (folding into the quarter loop blew
// the L2 reuse window: FETCH 30->107 MB in r11). Gather: quarter-wave (16
// lanes/node, uint4, 4 chains) with exact 8/4/2/1 batches. sIdx dbuf prefetch
// one relation ahead; inv prestaged; offs hoisted. Bucket-boundary ends come
// from bend[] (offs is bucket-relative; key windows never straddle buckets:
// 16-aligned, 1024 % 16 == 0).
// LDS: fH 16K + sQ 16K + sIdx 6K + sInv 1K + sMeta = 40000 B -> 4 blocks/CU.

constexpr int ICAP = 192;   // per-wave sIdx capacity (wcnt avg 96, sd ~10)

template<int LAST>
__global__ __launch_bounds__(256, 4) void k_layer(const u16* __restrict__ hin,
                                                  u16* __restrict__ houtH,
                                                  float* __restrict__ outF,
                                                  const u16* __restrict__ wtH,
                                                  const float* __restrict__ bias,
                                                  const u16* __restrict__ sorted,
                                                  const int* __restrict__ offs,
                                                  const float* __restrict__ inv,
                                                  const int* __restrict__ bend) {
    __shared__ __align__(16) u16 fH[4 * 2048];   // 16 KB A-frags (swizzled, wave-private)
    __shared__ __align__(16) u16 sQ[2][4096];    // 2 x 8 KB B k-quarter buffers
    __shared__ int   sIdx[2][4 * ICAP];          // 6 KB dbuf gather indices
    __shared__ float sInv[4 * 64];               // 1 KB prestaged inverse counts
    __shared__ int   sMeta[2][4][2];             // (w0, w1) per buf/wave

    int tid  = threadIdx.x;
    int wave = tid >> 6, lane = tid & 63;
    int mm   = lane & 15;            // MFMA m/n lane; gather col-octet
    int qd   = lane >> 4;            // MFMA quad; gather quarter (node group)
    int row0 = blockIdx.x * 64;
    int wbU  = wave * 2048;          // fH wave base (u16)

    f32x4 acc[8];
#pragma unroll
    for (int i = 0; i < 8; ++i) acc[i] = (f32x4){0.f, 0.f, 0.f, 0.f};

    // granule slot for A-frag: f(node, ks, g) = ks*64 + g*16 + (node ^ (ks*4+g))
    auto writeFragQ = [&](int node, uint4 u) {   // lane's cols = mm*8..+7
        int ks = mm >> 2, g = mm & 3;
        int slot = ks * 64 + g * 16 + (node ^ (ks * 4 + g));
        *(uint4*)&fH[wbU + slot * 8] = u;
    };
    auto loadA = [&](bf16x8* AH) {
#pragma unroll
        for (int ks = 0; ks < 4; ++ks) {
            int slot = ks * 64 + qd * 16 + (mm ^ (ks * 4 + qd));
            AH[ks] = *(const bf16x8*)&fH[wbU + slot * 8];
        }
    };

    // stage k-quarter `step` (mat step>>2, cols (step&3)*32..) into sQ[bufi]
    auto stage = [&](int step, int bufi) {
        const u16* src = wtH + (step >> 2) * 16384 + (step & 3) * 32;
#pragma unroll
        for (int i = 0; i < 2; ++i) {            // 512 granules, 2/thread
            int u = i * 256 + tid;
            int n = u >> 2, j = u & 3;
            gl_lds16(src + n * 128 + ((j ^ ((n >> 1) & 3)) * 8), &sQ[bufi][u * 8]);
        }
    };
    auto mfma_quarter = [&](int bufi, bf16x8 A) {
        const u16* buf = sQ[bufi];
#pragma unroll
        for (int nt = 0; nt < 8; ++nt) {
            int n = nt * 16 + mm;
            int slot = n * 4 + (qd ^ ((n >> 1) & 3));
            bf16x8 B = *(const bf16x8*)&buf[slot * 8];
            acc[nt] = __builtin_amdgcn_mfma_f32_16x16x32_bf16(A, B, acc[nt], 0, 0, 0);
        }
    };

    // prefetch relation g's sorted-index range into sIdx[sbuf] (wave-private)
    auto prefetchIdx = [&](int g, int sbuf) {
        int bidx0 = g * NN + row0 + wave * 16;
        int w0 = offs[bidx0];
        int i16 = bidx0 + 16;
        int w1 = ((i16 & 1023) == 0) ? bend[bidx0 >> 10] : offs[i16];
        if (lane == 0) { sMeta[sbuf][wave][0] = w0; sMeta[sbuf][wave][1] = w1; }
        int wcnt = w1 - w0;
        if (wcnt > ICAP) wcnt = ICAP;            // fallback handled in gather
        for (int i = lane; i < wcnt; i += 64)
            sIdx[sbuf][wave * ICAP + i] = (int)sorted[w0 + i];
    };

    // per-relation mean-aggregate, quarter-wave: 4 nodes in flight
    auto gather = [&](int g, int sbuf) {
        int bidx0 = g * NN + row0 + wave * 16;
        int w0 = sMeta[sbuf][wave][0];
        int w1 = sMeta[sbuf][wave][1];
        bool fits = (w1 - w0 <= ICAP);
        const int* si = &sIdx[sbuf][wave * ICAP];

        // hoist all 8 offs loads (independent; issue together)
        int r0v[4], r1v[4];
#pragma unroll
        for (int t2 = 0; t2 < 4; ++t2) {
            int b = bidx0 + t2 * 4 + qd;
            r0v[t2] = offs[b];
            const int* pe = (((b + 1) & 1023) == 0) ? &bend[b >> 10] : &offs[b + 1];
            r1v[t2] = *pe;
        }

#pragma unroll
        for (int t2 = 0; t2 < 4; ++t2) {
            int node = t2 * 4 + qd;
            int r0 = r0v[t2], r1 = r1v[t2];
            int o  = r0 - w0;
            int cnt = r1 - r0;
            float ax[8];
#pragma unroll
            for (int i = 0; i < 8; ++i) ax[i] = 0.f;

            auto upk = [&](uint4 u) {
                ax[0] += __uint_as_float(u.x << 16);
                ax[1] += __uint_as_float(u.x & 0xffff0000u);
                ax[2] += __uint_as_float(u.y << 16);
                ax[3] += __uint_as_float(u.y & 0xffff0000u);
                ax[4] += __uint_as_float(u.z << 16);
                ax[5] += __uint_as_float(u.z & 0xffff0000u);
                ax[6] += __uint_as_float(u.w << 16);
                ax[7] += __uint_as_float(u.w & 0xffff0000u);
            };

            int j = 0;
            if (fits) {
                for (; j + 8 <= cnt; j += 8) {   // exact batches: 8 / 4 / 2 / 1
                    uint4 v0 = *(const uint4*)&hin[si[o+j+0] * DD + mm * 8];
                    uint4 v1 = *(const uint4*)&hin[si[o+j+1] * DD + mm * 8];
                    uint4 v2 = *(const uint4*)&hin[si[o+j+2] * DD + mm * 8];
                    uint4 v3 = *(const uint4*)&hin[si[o+j+3] * DD + mm * 8];
                    uint4 v4 = *(const uint4*)&hin[si[o+j+4] * DD + mm * 8];
                    uint4 v5 = *(const uint4*)&hin[si[o+j+5] * DD + mm * 8];
                    uint4 v6 = *(const uint4*)&hin[si[o+j+6] * DD + mm * 8];
                    uint4 v7 = *(const uint4*)&hin[si[o+j+7] * DD + mm * 8];
                    upk(v0); upk(v1); upk(v2); upk(v3);
                    upk(v4); upk(v5); upk(v6); upk(v7);
                }
                if (j + 4 <= cnt) {
                    uint4 v0 = *(const uint4*)&hin[si[o+j+0] * DD + mm * 8];
                    uint4 v1 = *(const uint4*)&hin[si[o+j+1] * DD + mm * 8];
                    uint4 v2 = *(const uint4*)&hin[si[o+j+2] * DD + mm * 8];
                    uint4 v3 = *(const uint4*)&hin[si[o+j+3] * DD + mm * 8];
                    upk(v0); upk(v1); upk(v2); upk(v3);
                    j += 4;
                }
                if (j + 2 <= cnt) {
                    uint4 v0 = *(const uint4*)&hin[si[o+j+0] * DD + mm * 8];
                    uint4 v1 = *(const uint4*)&hin[si[o+j+1] * DD + mm * 8];
                    upk(v0); upk(v1);
                    j += 2;
                }
                if (j < cnt)
                    upk(*(const uint4*)&hin[si[o+j] * DD + mm * 8]);
            } else {
                for (; j + 4 <= cnt; j += 4) {
                    uint4 v0 = *(const uint4*)&hin[(int)sorted[r0+j+0] * DD + mm * 8];
                    uint4 v1 = *(const uint4*)&hin[(int)sorted[r0+j+1] * DD + mm * 8];
                    uint4 v2 = *(const uint4*)&hin[(int)sorted[r0+j+2] * DD + mm * 8];
                    uint4 v3 = *(const uint4*)&hin[(int)sorted[r0+j+3] * DD + mm * 8];
                    upk(v0); upk(v1); upk(v2); upk(v3);
                }
                if (j + 2 <= cnt) {
                    uint4 v0 = *(const uint4*)&hin[(int)sorted[r0+j+0] * DD + mm * 8];
                    uint4 v1 = *(const uint4*)&hin[(int)sorted[r0+j+1] * DD + mm * 8];
                    upk(v0); upk(v1);
                    j += 2;
                }
                if (j < cnt)
                    upk(*(const uint4*)&hin[(int)sorted[r0+j] * DD + mm * 8]);
            }
            float s = sInv[wave * 64 + g * 16 + node];
            u32 h0 = bf16_rne(ax[0] * s), h1 = bf16_rne(ax[1] * s);
            u32 h2 = bf16_rne(ax[2] * s), h3 = bf16_rne(ax[3] * s);
            u32 h4 = bf16_rne(ax[4] * s), h5 = bf16_rne(ax[5] * s);
            u32 h6 = bf16_rne(ax[6] * s), h7 = bf16_rne(ax[7] * s);
            uint4 pk;
            pk.x = h0 | (h1 << 16); pk.y = h2 | (h3 << 16);
            pk.z = h4 | (h5 << 16); pk.w = h6 | (h7 << 16);
            writeFragQ(node, pk);
        }
    };

    // ---- prologue ----
    prefetchIdx(0, 0);                           // relation 0 indices
    stage(0, 0);                                 // mat0 quarter0 DMA
    {   // prestage inv for all 4 relations (1 load/lane, wave-private)
        int g = lane >> 4, node = lane & 15;
        sInv[wave * 64 + lane] = inv[g * NN + row0 + wave * 16 + node];
    }
#pragma unroll
    for (int t2 = 0; t2 < 4; ++t2) {             // root A-frags (hin already bf16)
        int node = t2 * 4 + qd;
        uint4 u = *(const uint4*)&hin[(row0 + wave * 16 + node) * DD + mm * 8];
        writeFragQ(node, u);
    }
    __syncthreads();                             // buf0 DMA drained

    // ---- 5 matrices: mat0 = root, mat 1..4 = rel 0..3 ----
    for (int m = 0; m < 5; ++m) {
        bf16x8 AH[4];
        loadA(AH);
#pragma unroll
        for (int q = 0; q < 4; ++q) {
            int step = m * 4 + q;
            if (step + 1 < 20) stage(step + 1, (step + 1) & 1);
            mfma_quarter(step & 1, AH[q]);
            __syncthreads();                     // next buf drained; this buf free
        }
        if (m < 4) {
            if (m + 1 < 4) prefetchIdx(m + 1, (m + 1) & 1);  // hide idx latency
            gather(m, m & 1);                    // refill fH (wave-private; AH dead)
        }
    }

    // ---- epilogue ----
    float bvv[8];
#pragma unroll
    for (int nt = 0; nt < 8; ++nt) bvv[nt] = bias[nt * 16 + mm];

    if constexpr (LAST) {
        int gidx = row0 >> 7;                    // 64-node blocks never straddle graphs
#pragma unroll
        for (int nt = 0; nt < 8; ++nt) {
            float v0 = acc[nt][0], v1 = acc[nt][1], v2 = acc[nt][2], v3 = acc[nt][3];
            float v = fmaxf(fmaxf(v0, v1), fmaxf(v2, v3)) + bvv[nt];
            v = fmaxf(v, 0.f);                   // relu(max) == max(relu) per column
            v = fmaxf(v, __shfl_xor(v, 16));
            v = fmaxf(v, __shfl_xor(v, 32));
            if (lane < 16)
                atomicMax((u32*)&outF[gidx * DD + nt * 16 + mm], __float_as_uint(v));
        }
    } else {
        u16* fs = &fH[wbU];                      // bounce for coalesced bf16 rows
#pragma unroll
        for (int nt = 0; nt < 8; ++nt)
#pragma unroll
            for (int r = 0; r < 4; ++r)
                fs[(qd * 4 + r) * 128 + nt * 16 + mm] =
                    (u16)bf16_rne(fmaxf(acc[nt][r] + bvv[nt], 0.f));
        uint4* dst = (uint4*)&houtH[(row0 + wave * 16) * DD];
        const uint4* src = (const uint4*)fs;
#pragma unroll
        for (int i = 0; i < 4; ++i) dst[i * 64 + lane] = src[i * 64 + lane];
    }
}

// ---------------- launch ----------------

extern "C" void kernel_launch(void* const* d_in, const int* in_sizes, int n_in,
                              void* d_out, int out_size, void* d_ws, size_t ws_size,
                              hipStream_t stream) {
    const float* x      = (const float*)d_in[0];
    const int*   ei     = (const int*)  d_in[1];
    const int*   ea     = (const int*)  d_in[2];
    const float* W_emb  = (const float*)d_in[3];
    const float* b_emb  = (const float*)d_in[4];
    const float* W_root = (const float*)d_in[5];
    const float* W_rel  = (const float*)d_in[6];
    const float* bias   = (const float*)d_in[7];
    float* out = (float*)d_out;

    char* p = (char*)d_ws;
    u16*      h0H    = (u16*)p;      p += (size_t)NN * DD * 2;      // 16.78 MB
    u16*      h1H    = (u16*)p;      p += (size_t)NN * DD * 2;      // 16.78 MB
    u32*      bcur   = (u32*)p;      p += 1024;                     // bucket cursors (memset 0)
    int*      bend   = (int*)p;      p += 1024;                     // bucket end sentinels
    float*    inv    = (float*)p;    p += (size_t)NRSEG * 4;        // 1 MB
    int*      offs   = (int*)p;      p += (size_t)NRSEG * 4;        // 1 MB
    u32*      binned = (u32*)p;      p += (size_t)256 * BSZ * 4;    // 8.39 MB static slices
    u16*      sorted = (u16*)p;      p += (size_t)256 * BSZ * 2;    // 4.19 MB static slices
    u16*      wtH    = (u16*)p;      p += (size_t)10 * 16384 * 2;   // 0.33 MB

    hipMemsetAsync(bcur, 0, 1024, stream);

    k_front<<<1920, 256, 0, stream>>>(x, W_emb, b_emb, h0H, ei, ea, bcur, binned,
                                      W_root, W_rel, wtH, out);
    k_binB <<<256, 256, 0, stream>>>(binned, bcur, offs, inv, sorted, bend);

    k_layer<0><<<NN / 64, 256, 0, stream>>>(h0H, h1H, nullptr,
                                            wtH, bias, sorted, offs, inv, bend);
    k_layer<1><<<NN / 64, 256, 0, stream>>>(h1H, nullptr, out,
                                            wtH + 81920, bias + 128,
                                            sorted, offs, inv, bend);
}

// Round 14
// 257.783 us; speedup vs baseline: 1.2805x; 1.0454x over previous
//
#include <hip/hip_runtime.h>

// Problem constants
constexpr int GG    = 512;          // graphs
constexpr int NPG   = 128;          // nodes per graph
constexpr int FIN   = 64;
constexpr int DD    = 128;
constexpr int RR    = 4;
constexpr int NN    = GG * NPG;     // 65536 nodes
constexpr int EE    = 1572864;      // edges
constexpr int NRSEG = NN * RR;      // 262144 segments (key = r*NN + dst)
constexpr int BSZ   = 8192;         // static bucket slice (avg fill 6144, sd ~78)
constexpr int BCAP  = 7680;         // LDS staging capacity in k_binB
constexpr int HSTR  = 136;          // hG padded row stride in u16 (68 dwords)
constexpr int ICAP  = 192;          // per-(wave,rel) sIdx capacity (avg 96, sd ~10)

typedef __attribute__((ext_vector_type(8))) short bf16x8;
typedef __attribute__((ext_vector_type(4))) float f32x4;
typedef unsigned short u16;
typedef unsigned int   u32;

__device__ __forceinline__ u32 bf16_rne(float x) {
    u32 u = __float_as_uint(x);
    return (u + 0x7FFFu + ((u >> 16) & 1u)) >> 16;
}

// async global->LDS DMA, 16 B per lane; LDS side must be uniform-base + lane*16
__device__ __forceinline__ void gl_lds16(const void* g, void* l) {
    __builtin_amdgcn_global_load_lds((const __attribute__((address_space(1))) u32*)g,
                                     (__attribute__((address_space(3))) u32*)l, 16, 0, 0);
}

// ---------------- fused front: embed + binA + prep ---------------------------
// blocks [0,1024): embed | [1024,1216): binA | [1216,1856): prep.
// Static bucket slices: bucket b owns binned[b*8192..+8192); bcur = relative
// cursors (memset-0). No out-zero needed anymore (k_fused plain-stores out).

__global__ __launch_bounds__(256, 2) void k_front(const float* __restrict__ x,
                                                  const float* __restrict__ W_emb,
                                                  const float* __restrict__ b_emb,
                                                  u16* __restrict__ h,
                                                  const int* __restrict__ ei,
                                                  const int* __restrict__ ea,
                                                  u32* __restrict__ bcur,
                                                  u32* __restrict__ binned,
                                                  const float* __restrict__ W_root,
                                                  const float* __restrict__ W_rel,
                                                  u16* __restrict__ wtH) {
    __shared__ float sA[16 * 64];
    __shared__ float sB[16 * 128];
    __shared__ int bh[256];
    __shared__ int lcur[256];
    int tid = threadIdx.x;
    int bid = blockIdx.x;

    if (bid < 1024) {
        // ---- embed: h = bf16(x @ W_emb + b_emb) ----
        int tx = tid & 31, ty = tid >> 5;
        int row0 = bid * 64;
        float4 bv = *(const float4*)&b_emb[tx * 4];
        float acc[8][4];
#pragma unroll
        for (int i = 0; i < 8; ++i) { acc[i][0]=bv.x; acc[i][1]=bv.y; acc[i][2]=bv.z; acc[i][3]=bv.w; }
        for (int kb = 0; kb < 4; ++kb) {
            {
                int rr = tid >> 2, kq = tid & 3;
                float4 v = *(const float4*)&x[(row0 + rr) * FIN + kb * 16 + kq * 4];
                sA[(kq*4+0)*64 + rr] = v.x;
                sA[(kq*4+1)*64 + rr] = v.y;
                sA[(kq*4+2)*64 + rr] = v.z;
                sA[(kq*4+3)*64 + rr] = v.w;
            }
#pragma unroll
            for (int i = 0; i < 2; ++i) {
                int f = tid + i * 256;
                *(float4*)&sB[f * 4] = *(const float4*)&W_emb[kb * 16 * 128 + f * 4];
            }
            __syncthreads();
#pragma unroll
            for (int kk = 0; kk < 16; ++kk) {
                float4 a0 = *(const float4*)&sA[kk * 64 + ty * 4];
                float4 a1 = *(const float4*)&sA[kk * 64 + 32 + ty * 4];
                float4 bq = *(const float4*)&sB[kk * 128 + tx * 4];
                float ar[8] = {a0.x,a0.y,a0.z,a0.w,a1.x,a1.y,a1.z,a1.w};
#pragma unroll
                for (int i = 0; i < 8; ++i) {
                    acc[i][0] = fmaf(ar[i], bq.x, acc[i][0]);
                    acc[i][1] = fmaf(ar[i], bq.y, acc[i][1]);
                    acc[i][2] = fmaf(ar[i], bq.z, acc[i][2]);
                    acc[i][3] = fmaf(ar[i], bq.w, acc[i][3]);
                }
            }
            __syncthreads();
        }
#pragma unroll
        for (int i = 0; i < 8; ++i) {
            int row = (i < 4) ? (ty * 4 + i) : (32 + ty * 4 + (i - 4));
            u32 s0 = bf16_rne(acc[i][0]), s1 = bf16_rne(acc[i][1]);
            u32 s2 = bf16_rne(acc[i][2]), s3 = bf16_rne(acc[i][3]);
            *(uint2*)&h[(row0 + row) * DD + tx * 4] = make_uint2(s0 | (s1 << 16), s2 | (s3 << 16));
        }
    } else if (bid < 1216) {
        // ---- binA: LDS histogram -> per-(block,bucket) run reservation ----
        int e0 = (bid - 1024) * 8192;          // 192 blocks cover EE exactly
        bh[tid] = 0;
        __syncthreads();
        for (int i = 0; i < 32; ++i) {
            int e = e0 + i * 256 + tid;
            int dst = ei[EE + e];
            int a   = ea[e];
            atomicAdd(&bh[(a << 6) | (dst >> 10)], 1);
        }
        __syncthreads();
        lcur[tid] = tid * BSZ + (int)atomicAdd(&bcur[tid], (u32)bh[tid]);
        __syncthreads();
        for (int i = 0; i < 32; ++i) {
            int e = e0 + i * 256 + tid;
            int src = ei[e];
            int dst = ei[EE + e];
            int a   = ea[e];
            int pos = atomicAdd(&lcur[(a << 6) | (dst >> 10)], 1);
            binned[pos] = (u32)src | ((u32)dst << 16);
        }
    } else {
        // ---- prep: transpose weights to bf16, wt[mat*16384 + n*128 + k] ----
        int idx = (bid - 1216) * 256 + tid;    // covers 10*16384
        int mat = idx >> 14;
        int rem = idx & 16383;
        int n = rem >> 7, k = rem & 127;
        int l = mat / 5, m5 = mat - l * 5;
        float v = (m5 == 0) ? W_root[l * 16384 + k * 128 + n]
                            : W_rel[((l * RR + (m5 - 1)) * 128 + k) * 128 + n];
        wtH[idx] = (u16)bf16_rne(v);
    }
}

// ---------------- binB: within-bucket sort + emit offs/inv/bend --------------

__global__ __launch_bounds__(256) void k_binB(const u32* __restrict__ binned,
                                              const u32* __restrict__ bcur,
                                              int* __restrict__ offs,
                                              float* __restrict__ inv,
                                              u16* __restrict__ sorted,
                                              int* __restrict__ bend) {
    __shared__ int pc[1024];
    __shared__ int ts[256];
    __shared__ u16 stg[BCAP];
    int tid = threadIdx.x;
    int b = blockIdx.x;
    int p0 = b * BSZ;
    int cnt = (int)bcur[b];
    if (cnt > BSZ) cnt = BSZ;                  // never in practice (26 sigma)
    bool fits = (cnt <= BCAP);
    if (tid == 0) bend[b] = p0 + cnt;

#pragma unroll
    for (int i = 0; i < 4; ++i) pc[i * 256 + tid] = 0;
    __syncthreads();
    for (int i = tid; i < cnt; i += 256) {
        u32 rec = binned[p0 + i];
        atomicAdd(&pc[(rec >> 16) & 1023], 1);
    }
    __syncthreads();
    int v[4], s = 0;
#pragma unroll
    for (int i = 0; i < 4; ++i) { v[i] = pc[tid * 4 + i]; s += v[i]; }
    ts[tid] = s;
    __syncthreads();
    for (int o = 1; o < 256; o <<= 1) {
        int t = (tid >= o) ? ts[tid - o] : 0;
        __syncthreads();
        ts[tid] += t;
        __syncthreads();
    }
    int ex = ts[tid] - s;
    {
        int4 o4; float4 i4;
        int e = ex;
#pragma unroll
        for (int i = 0; i < 4; ++i) {
            (&o4.x)[i] = p0 + e;
            (&i4.x)[i] = 1.0f / (float)(v[i] > 0 ? v[i] : 1);
            e += v[i];
        }
        *(int4*)&offs[(b << 10) + tid * 4]  = o4;
        *(float4*)&inv[(b << 10) + tid * 4] = i4;
    }
    __syncthreads();                            // counts consumed
#pragma unroll
    for (int i = 0; i < 4; ++i) { pc[tid * 4 + i] = ex; ex += v[i]; }
    __syncthreads();
    if (fits) {
        for (int i = tid; i < cnt; i += 256) {
            u32 rec = binned[p0 + i];
            int pos = atomicAdd(&pc[(rec >> 16) & 1023], 1);
            stg[pos] = (u16)(rec & 0xFFFFu);
        }
        __syncthreads();
        for (int i = tid; i < cnt; i += 256) sorted[p0 + i] = stg[i];
    } else {
        for (int i = tid; i < cnt; i += 256) {
            u32 rec = binned[p0 + i];
            int pos = atomicAdd(&pc[(rec >> 16) & 1023], 1);
            sorted[p0 + pos] = (u16)(rec & 0xFFFFu);
        }
    }
}

// ---------------- fused two-layer RGCN + max-pool: one block per graph -------
// 512 threads = 8 waves; wave owns a 16-node M-strip. The whole graph's h
// (128 rows) lives in LDS (hG, padded stride 136 u16 -> 68 dwords: gather and
// A-frag b128 reads are 2-way bank aliased = free). Both layers run in-block:
// gathers read hG (LDS latency, not L2); layer0 epilogue writes h1 back into
// hG; layer1 epilogue reduces column maxes in LDS and plain-stores out (no
// atomics, no out-zero). Weight staging = one 40-step dbuf DMA pipeline.
// sIdx holds all 4 relations as u16 LOCAL indices (graphs are 128-aligned:
// local = src & 127), prefetched once, reused by both layers.
// LDS total ~102.7 KB -> 1 block/CU (proven >64 KB OK since round 1).

__global__ __launch_bounds__(512, 2) void k_fused(const u16* __restrict__ h0,
                                                  float* __restrict__ outF,
                                                  const u16* __restrict__ wtH,
                                                  const float* __restrict__ bias,
                                                  const u16* __restrict__ sorted,
                                                  const int* __restrict__ offs,
                                                  const float* __restrict__ inv,
                                                  const int* __restrict__ bend) {
    __shared__ __align__(16) u16 hG[128 * HSTR];   // 34816 B current-layer h
    __shared__ __align__(16) u16 fH[8 * 2048];     // 32768 B A-frags (swizzled, wave-private)
    __shared__ __align__(16) u16 sQ[2][4096];      // 16384 B B k-quarter dbuf
    __shared__ u16   sIdx[RR][8 * ICAP];           // 12288 B local src idx (all 4 rels)
    __shared__ float sInv[8 * 64];                 //  2048 B inverse counts
    __shared__ int   sMeta[RR][8][2];              //   256 B (w0,w1)
    __shared__ float red[8][128];                  //  4096 B pool reduce

    int tid  = threadIdx.x;
    int wave = tid >> 6, lane = tid & 63;
    int mm   = lane & 15;            // MFMA m/n lane; gather col-octet
    int qd   = lane >> 4;            // MFMA quad; gather quarter (node group)
    int gr   = blockIdx.x;           // graph id
    int row0g = gr * NPG;            // global row base
    int strip = wave * 16;           // local node base of this wave
    int wbU  = wave * 2048;

    // granule slot for A-frag: f(node, ks, g) = ks*64 + g*16 + (node ^ (ks*4+g))
    auto writeFragQ = [&](int node, uint4 u) {
        int ks = mm >> 2, g = mm & 3;
        int slot = ks * 64 + g * 16 + (node ^ (ks * 4 + g));
        *(uint4*)&fH[wbU + slot * 8] = u;
    };
    auto loadA = [&](bf16x8* AH) {
#pragma unroll
        for (int ks = 0; ks < 4; ++ks) {
            int slot = ks * 64 + qd * 16 + (mm ^ (ks * 4 + qd));
            AH[ks] = *(const bf16x8*)&fH[wbU + slot * 8];
        }
    };

    // stage k-quarter `step` into sQ[bufi]: mat = step>>2 (0..9 spans L0+L1)
    auto stage = [&](int step, int bufi) {
        const u16* src = wtH + (step >> 2) * 16384 + (step & 3) * 32;
        int u = tid;                 // 512 granules, 1/thread
        int n = u >> 2, j = u & 3;
        gl_lds16(src + n * 128 + ((j ^ ((n >> 1) & 3)) * 8), &sQ[bufi][u * 8]);
    };

    f32x4 acc[8];
    auto mfma_quarter = [&](int bufi, bf16x8 A) {
        const u16* buf = sQ[bufi];
#pragma unroll
        for (int nt = 0; nt < 8; ++nt) {
            int n = nt * 16 + mm;
            int slot = n * 4 + (qd ^ ((n >> 1) & 3));
            bf16x8 B = *(const bf16x8*)&buf[slot * 8];
            acc[nt] = __builtin_amdgcn_mfma_f32_16x16x32_bf16(A, B, acc[nt], 0, 0, 0);
        }
    };

    // per-relation mean-aggregate from hG (LDS), quarter-wave, 8/4/2/1 batches
    auto gather = [&](int rel) {
        int bidx0 = rel * NN + row0g + strip;
        int w0 = sMeta[rel][wave][0];
        int w1 = sMeta[rel][wave][1];
        bool fits = (w1 - w0 <= ICAP);
        const u16* si = &sIdx[rel][wave * ICAP];

        int r0v[4], r1v[4];
#pragma unroll
        for (int t2 = 0; t2 < 4; ++t2) {         // 8 independent offs loads, early
            int b = bidx0 + t2 * 4 + qd;
            r0v[t2] = offs[b];
            const int* pe = (((b + 1) & 1023) == 0) ? &bend[b >> 10] : &offs[b + 1];
            r1v[t2] = *pe;
        }

#pragma unroll
        for (int t2 = 0; t2 < 4; ++t2) {
            int node = t2 * 4 + qd;
            int r0 = r0v[t2], r1 = r1v[t2];
            int o  = r0 - w0;
            int cnt = r1 - r0;
            float ax[8];
#pragma unroll
            for (int i = 0; i < 8; ++i) ax[i] = 0.f;

            auto upk = [&](uint4 u) {
                ax[0] += __uint_as_float(u.x << 16);
                ax[1] += __uint_as_float(u.x & 0xffff0000u);
                ax[2] += __uint_as_float(u.y << 16);
                ax[3] += __uint_as_float(u.y & 0xffff0000u);
                ax[4] += __uint_as_float(u.z << 16);
                ax[5] += __uint_as_float(u.z & 0xffff0000u);
                ax[6] += __uint_as_float(u.w << 16);
                ax[7] += __uint_as_float(u.w & 0xffff0000u);
            };
            auto ld = [&](int li) {              // row from LDS hG
                return *(const uint4*)&hG[li * HSTR + mm * 8];
            };

            int j = 0;
            if (fits) {
                for (; j + 8 <= cnt; j += 8) {
                    uint4 v0 = ld(si[o+j+0]); uint4 v1 = ld(si[o+j+1]);
                    uint4 v2 = ld(si[o+j+2]); uint4 v3 = ld(si[o+j+3]);
                    uint4 v4 = ld(si[o+j+4]); uint4 v5 = ld(si[o+j+5]);
                    uint4 v6 = ld(si[o+j+6]); uint4 v7 = ld(si[o+j+7]);
                    upk(v0); upk(v1); upk(v2); upk(v3);
                    upk(v4); upk(v5); upk(v6); upk(v7);
                }
                if (j + 4 <= cnt) {
                    uint4 v0 = ld(si[o+j+0]); uint4 v1 = ld(si[o+j+1]);
                    uint4 v2 = ld(si[o+j+2]); uint4 v3 = ld(si[o+j+3]);
                    upk(v0); upk(v1); upk(v2); upk(v3);
                    j += 4;
                }
                if (j + 2 <= cnt) {
                    uint4 v0 = ld(si[o+j+0]); uint4 v1 = ld(si[o+j+1]);
                    upk(v0); upk(v1);
                    j += 2;
                }
                if (j < cnt) upk(ld(si[o+j]));
            } else {
                for (; j + 4 <= cnt; j += 4) {
                    uint4 v0 = ld((int)sorted[r0+j+0] & 127);
                    uint4 v1 = ld((int)sorted[r0+j+1] & 127);
                    uint4 v2 = ld((int)sorted[r0+j+2] & 127);
                    uint4 v3 = ld((int)sorted[r0+j+3] & 127);
                    upk(v0); upk(v1); upk(v2); upk(v3);
                }
                for (; j < cnt; ++j) upk(ld((int)sorted[r0+j] & 127));
            }
            float s = sInv[wave * 64 + rel * 16 + node];
            u32 h0v = bf16_rne(ax[0] * s), h1v = bf16_rne(ax[1] * s);
            u32 h2v = bf16_rne(ax[2] * s), h3v = bf16_rne(ax[3] * s);
            u32 h4v = bf16_rne(ax[4] * s), h5v = bf16_rne(ax[5] * s);
            u32 h6v = bf16_rne(ax[6] * s), h7v = bf16_rne(ax[7] * s);
            uint4 pk;
            pk.x = h0v | (h1v << 16); pk.y = h2v | (h3v << 16);
            pk.z = h4v | (h5v << 16); pk.w = h6v | (h7v << 16);
            writeFragQ(node, pk);
        }
    };

    // ---- prologue ----
    stage(0, 0);                                 // (L0, mat0, q0) DMA
    for (int r = 0; r < RR; ++r) {               // all 4 relations' indices (local)
        int bidx0 = r * NN + row0g + strip;
        int w0 = offs[bidx0];
        int i16 = bidx0 + 16;
        int w1 = ((i16 & 1023) == 0) ? bend[bidx0 >> 10] : offs[i16];
        if (lane == 0) { sMeta[r][wave][0] = w0; sMeta[r][wave][1] = w1; }
        int wcnt = w1 - w0;
        if (wcnt > ICAP) wcnt = ICAP;
        for (int i = lane; i < wcnt; i += 64)
            sIdx[r][wave * ICAP + i] = (u16)(sorted[w0 + i] & 127);
    }
    {   // inv for this wave's 16 nodes x 4 relations
        int r = lane >> 4, node = lane & 15;
        sInv[wave * 64 + lane] = inv[r * NN + row0g + strip + node];
    }
    for (int i = tid; i < 128 * 16; i += 512) {  // stage hG = h0 graph rows
        int row = i >> 4, c = i & 15;
        *(uint4*)&hG[row * HSTR + c * 8] =
            *(const uint4*)&h0[(size_t)(row0g + row) * DD + c * 8];
    }
    __syncthreads();                             // hG + buf0 DMA ready

    // ---- two layers x 5 matrices ----
    for (int L = 0; L < 2; ++L) {
        const float* bl = bias + L * DD;
#pragma unroll
        for (int i = 0; i < 8; ++i) acc[i] = (f32x4){0.f, 0.f, 0.f, 0.f};

        for (int m = 0; m < 5; ++m) {
            bf16x8 AH[4];
            if (m == 0) {                        // root A direct from hG
#pragma unroll
                for (int ks = 0; ks < 4; ++ks)
                    AH[ks] = *(const bf16x8*)&hG[(strip + mm) * HSTR + ks * 32 + qd * 8];
            } else {
                loadA(AH);
            }
#pragma unroll
            for (int q = 0; q < 4; ++q) {
                int step = L * 20 + m * 4 + q;
                if (step + 1 < 40) stage(step + 1, (step + 1) & 1);
                mfma_quarter(step & 1, AH[q]);
                __syncthreads();                 // next buf drained; this buf free
            }
            if (m < 4) gather(m);                // reads hG; writes wave-private fH
        }

        if (L == 0) {
            // h1 -> hG (all hG readers passed the mat4 barriers)
#pragma unroll
            for (int nt = 0; nt < 8; ++nt) {
                float bv = bl[nt * 16 + mm];
#pragma unroll
                for (int r = 0; r < 4; ++r)
                    hG[(strip + qd * 4 + r) * HSTR + nt * 16 + mm] =
                        (u16)bf16_rne(fmaxf(acc[nt][r] + bv, 0.f));
            }
            __syncthreads();                     // h1 visible to all waves
        } else {
            // max-pool: per-wave column max -> LDS -> plain store
#pragma unroll
            for (int nt = 0; nt < 8; ++nt) {
                float bv = bl[nt * 16 + mm];
                float v = fmaxf(fmaxf(acc[nt][0], acc[nt][1]),
                                fmaxf(acc[nt][2], acc[nt][3])) + bv;
                v = fmaxf(v, 0.f);               // relu(max) == max(relu)
                v = fmaxf(v, __shfl_xor(v, 16));
                v = fmaxf(v, __shfl_xor(v, 32));
                if (lane < 16) red[wave][nt * 16 + mm] = v;
            }
            __syncthreads();
            if (tid < 128) {
                float mx = red[0][tid];
#pragma unroll
                for (int w = 1; w < 8; ++w) mx = fmaxf(mx, red[w][tid]);
                outF[gr * DD + tid] = mx;
            }
        }
    }
}

// ---------------- launch ----------------

extern "C" void kernel_launch(void* const* d_in, const int* in_sizes, int n_in,
                              void* d_out, int out_size, void* d_ws, size_t ws_size,
                              hipStream_t stream) {
    const float* x      = (const float*)d_in[0];
    const int*   ei     = (const int*)  d_in[1];
    const int*   ea     = (const int*)  d_in[2];
    const float* W_emb  = (const float*)d_in[3];
    const float* b_emb  = (const float*)d_in[4];
    const float* W_root = (const float*)d_in[5];
    const float* W_rel  = (const float*)d_in[6];
    const float* bias   = (const float*)d_in[7];
    float* out = (float*)d_out;

    char* p = (char*)d_ws;
    u16*      h0H    = (u16*)p;      p += (size_t)NN * DD * 2;      // 16.78 MB
    u32*      bcur   = (u32*)p;      p += 1024;                     // bucket cursors (memset 0)
    int*      bend   = (int*)p;      p += 1024;                     // bucket end sentinels
    float*    inv    = (float*)p;    p += (size_t)NRSEG * 4;        // 1 MB
    int*      offs   = (int*)p;      p += (size_t)NRSEG * 4;        // 1 MB
    u32*      binned = (u32*)p;      p += (size_t)256 * BSZ * 4;    // 8.39 MB static slices
    u16*      sorted = (u16*)p;      p += (size_t)256 * BSZ * 2;    // 4.19 MB static slices
    u16*      wtH    = (u16*)p;      p += (size_t)10 * 16384 * 2;   // 0.33 MB

    hipMemsetAsync(bcur, 0, 1024, stream);

    k_front<<<1856, 256, 0, stream>>>(x, W_emb, b_emb, h0H, ei, ea, bcur, binned,
                                      W_root, W_rel, wtH);
    k_binB <<<256, 256, 0, stream>>>(binned, bcur, offs, inv, sorted, bend);
    k_fused<<<GG, 512, 0, stream>>>(h0H, out, wtH, bias, sorted, offs, inv, bend);
}

// Round 15
// 244.055 us; speedup vs baseline: 1.3526x; 1.0563x over previous
//
#include <hip/hip_runtime.h>

// Problem constants
constexpr int GG    = 512;          // graphs
constexpr int NPG   = 128;          // nodes per graph
constexpr int FIN   = 64;
constexpr int DD    = 128;
constexpr int RR    = 4;
constexpr int NN    = GG * NPG;     // 65536 nodes
constexpr int EE    = 1572864;      // edges
constexpr int NRSEG = NN * RR;      // 262144 segments (key = r*NN + dst)
constexpr int BSZ   = 8192;         // static bucket slice (avg fill 6144, sd ~78)
constexpr int BCAP  = 7680;         // LDS staging capacity in k_binB
constexpr int HSTR  = 136;          // hG padded row stride in u16 (68 dwords)
constexpr int ICAP  = 192;          // per-(wave,rel) sIdx capacity (avg 96, sd ~10)

typedef __attribute__((ext_vector_type(8))) short bf16x8;
typedef __attribute__((ext_vector_type(4))) float f32x4;
typedef unsigned short u16;
typedef unsigned int   u32;

__device__ __forceinline__ u32 bf16_rne(float x) {
    u32 u = __float_as_uint(x);
    return (u + 0x7FFFu + ((u >> 16) & 1u)) >> 16;
}

// async global->LDS DMA, 16 B per lane; LDS side must be uniform-base + lane*16
__device__ __forceinline__ void gl_lds16(const void* g, void* l) {
    __builtin_amdgcn_global_load_lds((const __attribute__((address_space(1))) u32*)g,
                                     (__attribute__((address_space(3))) u32*)l, 16, 0, 0);
}

// ---------------- front: binA + prep (embed now lives in k_fused) ------------
// blocks [0,192): binA | [192,832): prep 10 layer mats | [832,864): prep wtE.
// Static bucket slices: bucket b owns binned[b*8192..+8192); bcur = relative
// cursors (memset-0).

__global__ __launch_bounds__(256, 2) void k_front(const int* __restrict__ ei,
                                                  const int* __restrict__ ea,
                                                  u32* __restrict__ bcur,
                                                  u32* __restrict__ binned,
                                                  const float* __restrict__ W_root,
                                                  const float* __restrict__ W_rel,
                                                  const float* __restrict__ W_emb,
                                                  u16* __restrict__ wtH) {
    __shared__ int bh[256];
    __shared__ int lcur[256];
    int tid = threadIdx.x;
    int bid = blockIdx.x;

    if (bid < 192) {
        // ---- binA: LDS histogram -> per-(block,bucket) run reservation ----
        int e0 = bid * 8192;                   // 192 blocks cover EE exactly
        bh[tid] = 0;
        __syncthreads();
        for (int i = 0; i < 32; ++i) {
            int e = e0 + i * 256 + tid;
            int dst = ei[EE + e];
            int a   = ea[e];
            atomicAdd(&bh[(a << 6) | (dst >> 10)], 1);
        }
        __syncthreads();
        lcur[tid] = tid * BSZ + (int)atomicAdd(&bcur[tid], (u32)bh[tid]);
        __syncthreads();
        for (int i = 0; i < 32; ++i) {
            int e = e0 + i * 256 + tid;
            int src = ei[e];
            int dst = ei[EE + e];
            int a   = ea[e];
            int pos = atomicAdd(&lcur[(a << 6) | (dst >> 10)], 1);
            binned[pos] = (u32)src | ((u32)dst << 16);
        }
    } else if (bid < 832) {
        // ---- prep: transpose layer weights to bf16, wt[mat*16384 + n*128 + k] ----
        int idx = (bid - 192) * 256 + tid;     // covers 10*16384
        int mat = idx >> 14;
        int rem = idx & 16383;
        int n = rem >> 7, k = rem & 127;
        int l = mat / 5, m5 = mat - l * 5;
        float v = (m5 == 0) ? W_root[l * 16384 + k * 128 + n]
                            : W_rel[((l * RR + (m5 - 1)) * 128 + k) * 128 + n];
        wtH[idx] = (u16)bf16_rne(v);
    } else {
        // ---- prep wtE = W_emb^T (128 n x 64 k) at wtH + 163840 ----
        int idx = (bid - 832) * 256 + tid;     // covers 8192
        int n = idx >> 6, k = idx & 63;
        wtH[163840 + idx] = (u16)bf16_rne(W_emb[k * DD + n]);
    }
}

// ---------------- binB: within-bucket sort + emit offs/inv/bend --------------

__global__ __launch_bounds__(256) void k_binB(const u32* __restrict__ binned,
                                              const u32* __restrict__ bcur,
                                              int* __restrict__ offs,
                                              float* __restrict__ inv,
                                              u16* __restrict__ sorted,
                                              int* __restrict__ bend) {
    __shared__ int pc[1024];
    __shared__ int ts[256];
    __shared__ u16 stg[BCAP];
    int tid = threadIdx.x;
    int b = blockIdx.x;
    int p0 = b * BSZ;
    int cnt = (int)bcur[b];
    if (cnt > BSZ) cnt = BSZ;                  // never in practice (26 sigma)
    bool fits = (cnt <= BCAP);
    if (tid == 0) bend[b] = p0 + cnt;

#pragma unroll
    for (int i = 0; i < 4; ++i) pc[i * 256 + tid] = 0;
    __syncthreads();
    for (int i = tid; i < cnt; i += 256) {
        u32 rec = binned[p0 + i];
        atomicAdd(&pc[(rec >> 16) & 1023], 1);
    }
    __syncthreads();
    int v[4], s = 0;
#pragma unroll
    for (int i = 0; i < 4; ++i) { v[i] = pc[tid * 4 + i]; s += v[i]; }
    ts[tid] = s;
    __syncthreads();
    for (int o = 1; o < 256; o <<= 1) {
        int t = (tid >= o) ? ts[tid - o] : 0;
        __syncthreads();
        ts[tid] += t;
        __syncthreads();
    }
    int ex = ts[tid] - s;
    {
        int4 o4; float4 i4;
        int e = ex;
#pragma unroll
        for (int i = 0; i < 4; ++i) {
            (&o4.x)[i] = p0 + e;
            (&i4.x)[i] = 1.0f / (float)(v[i] > 0 ? v[i] : 1);
            e += v[i];
        }
        *(int4*)&offs[(b << 10) + tid * 4]  = o4;
        *(float4*)&inv[(b << 10) + tid * 4] = i4;
    }
    __syncthreads();                            // counts consumed
#pragma unroll
    for (int i = 0; i < 4; ++i) { pc[tid * 4 + i] = ex; ex += v[i]; }
    __syncthreads();
    if (fits) {
        for (int i = tid; i < cnt; i += 256) {
            u32 rec = binned[p0 + i];
            int pos = atomicAdd(&pc[(rec >> 16) & 1023], 1);
            stg[pos] = (u16)(rec & 0xFFFFu);
        }
        __syncthreads();
        for (int i = tid; i < cnt; i += 256) sorted[p0 + i] = stg[i];
    } else {
        for (int i = tid; i < cnt; i += 256) {
            u32 rec = binned[p0 + i];
            int pos = atomicAdd(&pc[(rec >> 16) & 1023], 1);
            sorted[p0 + pos] = (u16)(rec & 0xFFFFu);
        }
    }
}

// ---------------- fused embed + two-layer RGCN + max-pool: block = graph -----
// 512 threads = 8 waves; wave owns a 16-node M-strip. Whole graph's h lives
// in LDS (hG, stride 136 u16 -> conflict-free b128 phases). NEW: the embed
// GEMM (h0 = x @ W_emb + b_emb) runs in-kernel: A-frags built per-lane from
// global x (f32 -> bf16, same (m,k) mapping as the root-A hG read), B = wtE
// staged through the same sQ dbuf pipeline (K=64 -> 2 quarter-steps), output
// written straight into hG. No h0 global round-trip; k_front has no embed.
// Gathers read hG (LDS); L0 epilogue writes h1 into hG; L1 epilogue reduces
// column maxes and plain-stores out (no atomics, no out-zero).

__global__ __launch_bounds__(512, 2) void k_fused(const float* __restrict__ x,
                                                  const float* __restrict__ b_emb,
                                                  float* __restrict__ outF,
                                                  const u16* __restrict__ wtH,
                                                  const float* __restrict__ bias,
                                                  const u16* __restrict__ sorted,
                                                  const int* __restrict__ offs,
                                                  const float* __restrict__ inv,
                                                  const int* __restrict__ bend) {
    __shared__ __align__(16) u16 hG[128 * HSTR];   // 34816 B current-layer h
    __shared__ __align__(16) u16 fH[8 * 2048];     // 32768 B A-frags (swizzled, wave-private)
    __shared__ __align__(16) u16 sQ[2][4096];      // 16384 B B k-quarter dbuf
    __shared__ u16   sIdx[RR][8 * ICAP];           // 12288 B local src idx (all 4 rels)
    __shared__ float sInv[8 * 64];                 //  2048 B inverse counts
    __shared__ int   sMeta[RR][8][2];              //   256 B (w0,w1)
    __shared__ float red[8][128];                  //  4096 B pool reduce

    int tid  = threadIdx.x;
    int wave = tid >> 6, lane = tid & 63;
    int mm   = lane & 15;            // MFMA m/n lane; gather col-octet
    int qd   = lane >> 4;            // MFMA quad; gather quarter (node group)
    int gr   = blockIdx.x;           // graph id
    int row0g = gr * NPG;            // global row base
    int strip = wave * 16;           // local node base of this wave
    int wbU  = wave * 2048;
    const u16* wtE = wtH + 163840;   // embed matrix (128 n x 64 k)

    // granule slot for A-frag: f(node, ks, g) = ks*64 + g*16 + (node ^ (ks*4+g))
    auto writeFragQ = [&](int node, uint4 u) {
        int ks = mm >> 2, g = mm & 3;
        int slot = ks * 64 + g * 16 + (node ^ (ks * 4 + g));
        *(uint4*)&fH[wbU + slot * 8] = u;
    };
    auto loadA = [&](bf16x8* AH) {
#pragma unroll
        for (int ks = 0; ks < 4; ++ks) {
            int slot = ks * 64 + qd * 16 + (mm ^ (ks * 4 + qd));
            AH[ks] = *(const bf16x8*)&fH[wbU + slot * 8];
        }
    };

    // stage k-quarter `step` into sQ[bufi]: layer mats, row stride 128
    auto stage = [&](int step, int bufi) {
        const u16* src = wtH + (step >> 2) * 16384 + (step & 3) * 32;
        int u = tid;                 // 512 granules, 1/thread
        int n = u >> 2, j = u & 3;
        gl_lds16(src + n * 128 + ((j ^ ((n >> 1) & 3)) * 8), &sQ[bufi][u * 8]);
    };
    // stage embed k-quarter q (K=64 mat, row stride 64)
    auto stageE = [&](int q, int bufi) {
        const u16* src = wtE + q * 32;
        int u = tid;
        int n = u >> 2, j = u & 3;
        gl_lds16(src + n * 64 + ((j ^ ((n >> 1) & 3)) * 8), &sQ[bufi][u * 8]);
    };

    f32x4 acc[8];
    auto mfma_quarter = [&](int bufi, bf16x8 A) {
        const u16* buf = sQ[bufi];
#pragma unroll
        for (int nt = 0; nt < 8; ++nt) {
            int n = nt * 16 + mm;
            int slot = n * 4 + (qd ^ ((n >> 1) & 3));
            bf16x8 B = *(const bf16x8*)&buf[slot * 8];
            acc[nt] = __builtin_amdgcn_mfma_f32_16x16x32_bf16(A, B, acc[nt], 0, 0, 0);
        }
    };

    // per-relation mean-aggregate from hG (LDS), quarter-wave, 8/4/2/1 batches
    auto gather = [&](int rel) {
        int bidx0 = rel * NN + row0g + strip;
        int w0 = sMeta[rel][wave][0];
        int w1 = sMeta[rel][wave][1];
        bool fits = (w1 - w0 <= ICAP);
        const u16* si = &sIdx[rel][wave * ICAP];

        int r0v[4], r1v[4];
#pragma unroll
        for (int t2 = 0; t2 < 4; ++t2) {         // 8 independent offs loads, early
            int b = bidx0 + t2 * 4 + qd;
            r0v[t2] = offs[b];
            const int* pe = (((b + 1) & 1023) == 0) ? &bend[b >> 10] : &offs[b + 1];
            r1v[t2] = *pe;
        }

#pragma unroll
        for (int t2 = 0; t2 < 4; ++t2) {
            int node = t2 * 4 + qd;
            int r0 = r0v[t2], r1 = r1v[t2];
            int o  = r0 - w0;
            int cnt = r1 - r0;
            float ax[8];
#pragma unroll
            for (int i = 0; i < 8; ++i) ax[i] = 0.f;

            auto upk = [&](uint4 u) {
                ax[0] += __uint_as_float(u.x << 16);
                ax[1] += __uint_as_float(u.x & 0xffff0000u);
                ax[2] += __uint_as_float(u.y << 16);
                ax[3] += __uint_as_float(u.y & 0xffff0000u);
                ax[4] += __uint_as_float(u.z << 16);
                ax[5] += __uint_as_float(u.z & 0xffff0000u);
                ax[6] += __uint_as_float(u.w << 16);
                ax[7] += __uint_as_float(u.w & 0xffff0000u);
            };
            auto ld = [&](int li) {              // row from LDS hG
                return *(const uint4*)&hG[li * HSTR + mm * 8];
            };

            int j = 0;
            if (fits) {
                for (; j + 8 <= cnt; j += 8) {
                    uint4 v0 = ld(si[o+j+0]); uint4 v1 = ld(si[o+j+1]);
                    uint4 v2 = ld(si[o+j+2]); uint4 v3 = ld(si[o+j+3]);
                    uint4 v4 = ld(si[o+j+4]); uint4 v5 = ld(si[o+j+5]);
                    uint4 v6 = ld(si[o+j+6]); uint4 v7 = ld(si[o+j+7]);
                    upk(v0); upk(v1); upk(v2); upk(v3);
                    upk(v4); upk(v5); upk(v6); upk(v7);
                }
                if (j + 4 <= cnt) {
                    uint4 v0 = ld(si[o+j+0]); uint4 v1 = ld(si[o+j+1]);
                    uint4 v2 = ld(si[o+j+2]); uint4 v3 = ld(si[o+j+3]);
                    upk(v0); upk(v1); upk(v2); upk(v3);
                    j += 4;
                }
                if (j + 2 <= cnt) {
                    uint4 v0 = ld(si[o+j+0]); uint4 v1 = ld(si[o+j+1]);
                    upk(v0); upk(v1);
                    j += 2;
                }
                if (j < cnt) upk(ld(si[o+j]));
            } else {
                for (; j + 4 <= cnt; j += 4) {
                    uint4 v0 = ld((int)sorted[r0+j+0] & 127);
                    uint4 v1 = ld((int)sorted[r0+j+1] & 127);
                    uint4 v2 = ld((int)sorted[r0+j+2] & 127);
                    uint4 v3 = ld((int)sorted[r0+j+3] & 127);
                    upk(v0); upk(v1); upk(v2); upk(v3);
                }
                for (; j < cnt; ++j) upk(ld((int)sorted[r0+j] & 127));
            }
            float s = sInv[wave * 64 + rel * 16 + node];
            u32 h0v = bf16_rne(ax[0] * s), h1v = bf16_rne(ax[1] * s);
            u32 h2v = bf16_rne(ax[2] * s), h3v = bf16_rne(ax[3] * s);
            u32 h4v = bf16_rne(ax[4] * s), h5v = bf16_rne(ax[5] * s);
            u32 h6v = bf16_rne(ax[6] * s), h7v = bf16_rne(ax[7] * s);
            uint4 pk;
            pk.x = h0v | (h1v << 16); pk.y = h2v | (h3v << 16);
            pk.z = h4v | (h5v << 16); pk.w = h6v | (h7v << 16);
            writeFragQ(node, pk);
        }
    };

    // ---- prologue ----
    stageE(0, 0);                                // embed quarter0 DMA
    for (int r = 0; r < RR; ++r) {               // all 4 relations' indices (local)
        int bidx0 = r * NN + row0g + strip;
        int w0 = offs[bidx0];
        int i16 = bidx0 + 16;
        int w1 = ((i16 & 1023) == 0) ? bend[bidx0 >> 10] : offs[i16];
        if (lane == 0) { sMeta[r][wave][0] = w0; sMeta[r][wave][1] = w1; }
        int wcnt = w1 - w0;
        if (wcnt > ICAP) wcnt = ICAP;
        for (int i = lane; i < wcnt; i += 64)
            sIdx[r][wave * ICAP + i] = (u16)(sorted[w0 + i] & 127);
    }
    {   // inv for this wave's 16 nodes x 4 relations
        int r = lane >> 4, node = lane & 15;
        sInv[wave * 64 + lane] = inv[r * NN + row0g + strip + node];
    }
    __syncthreads();                             // embed buf0 DMA drained

    // ---- embed: hG = bf16(x @ W_emb + b_emb), A from global x ----
    {
#pragma unroll
        for (int nt = 0; nt < 8; ++nt) {
            float bv = b_emb[nt * 16 + mm];
            acc[nt] = (f32x4){bv, bv, bv, bv};
        }
        bf16x8 AE[2];
#pragma unroll
        for (int ks = 0; ks < 2; ++ks) {         // k = ks*32 + qd*8 + 0..7
            const float* xp = &x[(size_t)(row0g + strip + mm) * FIN + ks * 32 + qd * 8];
            float4 a = *(const float4*)xp;
            float4 b = *(const float4*)(xp + 4);
            uint4 u;
            u.x = bf16_rne(a.x) | (bf16_rne(a.y) << 16);
            u.y = bf16_rne(a.z) | (bf16_rne(a.w) << 16);
            u.z = bf16_rne(b.x) | (bf16_rne(b.y) << 16);
            u.w = bf16_rne(b.z) | (bf16_rne(b.w) << 16);
            AE[ks] = *(bf16x8*)&u;
        }
        stageE(1, 1);
        mfma_quarter(0, AE[0]);
        __syncthreads();                         // buf1 drained; buf0 free
        stage(0, 0);                             // L0 mat0 q0 -> buf0
        mfma_quarter(1, AE[1]);
        __syncthreads();                         // buf0 drained; buf1 free
#pragma unroll
        for (int nt = 0; nt < 8; ++nt)           // write h0 rows into hG (no relu)
#pragma unroll
            for (int r = 0; r < 4; ++r)
                hG[(strip + qd * 4 + r) * HSTR + nt * 16 + mm] =
                    (u16)bf16_rne(acc[nt][r]);
        __syncthreads();                         // hG visible to all waves
    }

    // ---- two layers x 5 matrices ----
    for (int L = 0; L < 2; ++L) {
        const float* bl = bias + L * DD;
#pragma unroll
        for (int i = 0; i < 8; ++i) acc[i] = (f32x4){0.f, 0.f, 0.f, 0.f};

        for (int m = 0; m < 5; ++m) {
            bf16x8 AH[4];
            if (m == 0) {                        // root A direct from hG
#pragma unroll
                for (int ks = 0; ks < 4; ++ks)
                    AH[ks] = *(const bf16x8*)&hG[(strip + mm) * HSTR + ks * 32 + qd * 8];
            } else {
                loadA(AH);
            }
#pragma unroll
            for (int q = 0; q < 4; ++q) {
                int step = L * 20 + m * 4 + q;
                if (step + 1 < 40) stage(step + 1, (step + 1) & 1);
                mfma_quarter(step & 1, AH[q]);
                __syncthreads();                 // next buf drained; this buf free
            }
            if (m < 4) gather(m);                // reads hG; writes wave-private fH
        }

        if (L == 0) {
            // h1 -> hG (all hG readers passed the mat4 barriers)
#pragma unroll
            for (int nt = 0; nt < 8; ++nt) {
                float bv = bl[nt * 16 + mm];
#pragma unroll
                for (int r = 0; r < 4; ++r)
                    hG[(strip + qd * 4 + r) * HSTR + nt * 16 + mm] =
                        (u16)bf16_rne(fmaxf(acc[nt][r] + bv, 0.f));
            }
            __syncthreads();                     // h1 visible to all waves
        } else {
            // max-pool: per-wave column max -> LDS -> plain store
#pragma unroll
            for (int nt = 0; nt < 8; ++nt) {
                float bv = bl[nt * 16 + mm];
                float v = fmaxf(fmaxf(acc[nt][0], acc[nt][1]),
                                fmaxf(acc[nt][2], acc[nt][3])) + bv;
                v = fmaxf(v, 0.f);               // relu(max) == max(relu)
                v = fmaxf(v, __shfl_xor(v, 16));
                v = fmaxf(v, __shfl_xor(v, 32));
                if (lane < 16) red[wave][nt * 16 + mm] = v;
            }
            __syncthreads();
            if (tid < 128) {
                float mx = red[0][tid];
#pragma unroll
                for (int w = 1; w < 8; ++w) mx = fmaxf(mx, red[w][tid]);
                outF[gr * DD + tid] = mx;
            }
        }
    }
}

// ---------------- launch ----------------

extern "C" void kernel_launch(void* const* d_in, const int* in_sizes, int n_in,
                              void* d_out, int out_size, void* d_ws, size_t ws_size,
                              hipStream_t stream) {
    const float* x      = (const float*)d_in[0];
    const int*   ei     = (const int*)  d_in[1];
    const int*   ea     = (const int*)  d_in[2];
    const float* W_emb  = (const float*)d_in[3];
    const float* b_emb  = (const float*)d_in[4];
    const float* W_root = (const float*)d_in[5];
    const float* W_rel  = (const float*)d_in[6];
    const float* bias   = (const float*)d_in[7];
    float* out = (float*)d_out;

    char* p = (char*)d_ws;
    u32*      bcur   = (u32*)p;      p += 1024;                     // bucket cursors (memset 0)
    int*      bend   = (int*)p;      p += 1024;                     // bucket end sentinels
    float*    inv    = (float*)p;    p += (size_t)NRSEG * 4;        // 1 MB
    int*      offs   = (int*)p;      p += (size_t)NRSEG * 4;        // 1 MB
    u32*      binned = (u32*)p;      p += (size_t)256 * BSZ * 4;    // 8.39 MB static slices
    u16*      sorted = (u16*)p;      p += (size_t)256 * BSZ * 2;    // 4.19 MB static slices
    u16*      wtH    = (u16*)p;      p += (size_t)(10 * 16384 + 8192) * 2;  // 0.35 MB (+wtE)

    hipMemsetAsync(bcur, 0, 1024, stream);

    k_front<<<864, 256, 0, stream>>>(ei, ea, bcur, binned,
                                     W_root, W_rel, W_emb, wtH);
    k_binB <<<256, 256, 0, stream>>>(binned, bcur, offs, inv, sorted, bend);
    k_fused<<<GG, 512, 0, stream>>>(x, b_emb, out, wtH, bias,
                                    sorted, offs, inv, bend);
}

// Round 16
// 208.243 us; speedup vs baseline: 1.5852x; 1.1720x over previous
//
#include <hip/hip_runtime.h>

// Problem constants
constexpr int GG    = 512;          // graphs
constexpr int NPG   = 128;          // nodes per graph
constexpr int FIN   = 64;
constexpr int DD    = 128;
constexpr int RR    = 4;
constexpr int NN    = GG * NPG;     // 65536 nodes
constexpr int EE    = 1572864;      // edges
constexpr int NRSEG = NN * RR;      // 262144 segments (key = r*NN + dst)
constexpr int BSZ   = 8192;         // static bucket slice (avg fill 6144, sd ~78)
constexpr int BCAP  = 7680;         // LDS staging capacity in k_binB
constexpr int HSTR  = 136;          // hG padded row stride in u16 (68 dwords)
constexpr int ICAP  = 192;          // per-(wave,rel) sIdx capacity (avg 96, sd ~10)

typedef __attribute__((ext_vector_type(8))) short bf16x8;
typedef __attribute__((ext_vector_type(4))) float f32x4;
typedef unsigned short u16;
typedef unsigned int   u32;

__device__ __forceinline__ u32 bf16_rne(float x) {
    u32 u = __float_as_uint(x);
    return (u + 0x7FFFu + ((u >> 16) & 1u)) >> 16;
}

// async global->LDS DMA, 16 B per lane; LDS side must be uniform-base + lane*16
__device__ __forceinline__ void gl_lds16(const void* g, void* l) {
    __builtin_amdgcn_global_load_lds((const __attribute__((address_space(1))) u32*)g,
                                     (__attribute__((address_space(3))) u32*)l, 16, 0, 0);
}

// ---------------- front: binA + prep ----------------------------------------
// blocks [0,192): binA | [192,832): prep 10 layer mats | [832,864): prep wtE.

__global__ __launch_bounds__(256, 2) void k_front(const int* __restrict__ ei,
                                                  const int* __restrict__ ea,
                                                  u32* __restrict__ bcur,
                                                  u32* __restrict__ binned,
                                                  const float* __restrict__ W_root,
                                                  const float* __restrict__ W_rel,
                                                  const float* __restrict__ W_emb,
                                                  u16* __restrict__ wtH) {
    __shared__ int bh[256];
    __shared__ int lcur[256];
    int tid = threadIdx.x;
    int bid = blockIdx.x;

    if (bid < 192) {
        // ---- binA: LDS histogram -> per-(block,bucket) run reservation ----
        int e0 = bid * 8192;                   // 192 blocks cover EE exactly
        bh[tid] = 0;
        __syncthreads();
        for (int i = 0; i < 32; ++i) {
            int e = e0 + i * 256 + tid;
            int dst = ei[EE + e];
            int a   = ea[e];
            atomicAdd(&bh[(a << 6) | (dst >> 10)], 1);
        }
        __syncthreads();
        lcur[tid] = tid * BSZ + (int)atomicAdd(&bcur[tid], (u32)bh[tid]);
        __syncthreads();
        for (int i = 0; i < 32; ++i) {
            int e = e0 + i * 256 + tid;
            int src = ei[e];
            int dst = ei[EE + e];
            int a   = ea[e];
            int pos = atomicAdd(&lcur[(a << 6) | (dst >> 10)], 1);
            binned[pos] = (u32)src | ((u32)dst << 16);
        }
    } else if (bid < 832) {
        // ---- prep: transpose layer weights to bf16, wt[mat*16384 + n*128 + k] ----
        int idx = (bid - 192) * 256 + tid;     // covers 10*16384
        int mat = idx >> 14;
        int rem = idx & 16383;
        int n = rem >> 7, k = rem & 127;
        int l = mat / 5, m5 = mat - l * 5;
        float v = (m5 == 0) ? W_root[l * 16384 + k * 128 + n]
                            : W_rel[((l * RR + (m5 - 1)) * 128 + k) * 128 + n];
        wtH[idx] = (u16)bf16_rne(v);
    } else {
        // ---- prep wtE = W_emb^T (128 n x 64 k) at wtH + 163840 ----
        int idx = (bid - 832) * 256 + tid;     // covers 8192
        int n = idx >> 6, k = idx & 63;
        wtH[163840 + idx] = (u16)bf16_rne(W_emb[k * DD + n]);
    }
}

// ---------------- binB: within-bucket sort + emit offs/inv/bend --------------

__global__ __launch_bounds__(256) void k_binB(const u32* __restrict__ binned,
                                              const u32* __restrict__ bcur,
                                              int* __restrict__ offs,
                                              float* __restrict__ inv,
                                              u16* __restrict__ sorted,
                                              int* __restrict__ bend) {
    __shared__ int pc[1024];
    __shared__ int ts[256];
    __shared__ u16 stg[BCAP];
    int tid = threadIdx.x;
    int b = blockIdx.x;
    int p0 = b * BSZ;
    int cnt = (int)bcur[b];
    if (cnt > BSZ) cnt = BSZ;                  // never in practice (26 sigma)
    bool fits = (cnt <= BCAP);
    if (tid == 0) bend[b] = p0 + cnt;

#pragma unroll
    for (int i = 0; i < 4; ++i) pc[i * 256 + tid] = 0;
    __syncthreads();
    for (int i = tid; i < cnt; i += 256) {
        u32 rec = binned[p0 + i];
        atomicAdd(&pc[(rec >> 16) & 1023], 1);
    }
    __syncthreads();
    int v[4], s = 0;
#pragma unroll
    for (int i = 0; i < 4; ++i) { v[i] = pc[tid * 4 + i]; s += v[i]; }
    ts[tid] = s;
    __syncthreads();
    for (int o = 1; o < 256; o <<= 1) {
        int t = (tid >= o) ? ts[tid - o] : 0;
        __syncthreads();
        ts[tid] += t;
        __syncthreads();
    }
    int ex = ts[tid] - s;
    {
        int4 o4; float4 i4;
        int e = ex;
#pragma unroll
        for (int i = 0; i < 4; ++i) {
            (&o4.x)[i] = p0 + e;
            (&i4.x)[i] = 1.0f / (float)(v[i] > 0 ? v[i] : 1);
            e += v[i];
        }
        *(int4*)&offs[(b << 10) + tid * 4]  = o4;
        *(float4*)&inv[(b << 10) + tid * 4] = i4;
    }
    __syncthreads();                            // counts consumed
#pragma unroll
    for (int i = 0; i < 4; ++i) { pc[tid * 4 + i] = ex; ex += v[i]; }
    __syncthreads();
    if (fits) {
        for (int i = tid; i < cnt; i += 256) {
            u32 rec = binned[p0 + i];
            int pos = atomicAdd(&pc[(rec >> 16) & 1023], 1);
            stg[pos] = (u16)(rec & 0xFFFFu);
        }
        __syncthreads();
        for (int i = tid; i < cnt; i += 256) sorted[p0 + i] = stg[i];
    } else {
        for (int i = tid; i < cnt; i += 256) {
            u32 rec = binned[p0 + i];
            int pos = atomicAdd(&pc[(rec >> 16) & 1023], 1);
            sorted[p0 + pos] = (u16)(rec & 0xFFFFu);
        }
    }
}

// ---------------- fused embed + two-layer RGCN + max-pool: block = graph -----
// 512 threads = 8 waves; wave owns a 16-node M-strip; whole graph's h in LDS.
// NEW vs r15: fH (A-frag staging) is GONE. Gather is now A-layout-direct:
// lane (mm,qd) walks node strip+mm's edge list and accumulates cols
// {ks*32+qd*8..+7} (4x ds_read_b128/edge, 32 accumulators) -> the result IS
// the MFMA A-fragment, converted to bf16 in-register. 16 edges/iteration
// (vs 4), 2 offs loads/lane (vs 8), no fH write / loadA read. LDS drops
// 102.9 -> ~69.9 KB -> 2 blocks/CU (16 waves); __launch_bounds__(512,4)
// caps VGPR at 128 to keep that occupancy.

__global__ __launch_bounds__(512, 4) void k_fused(const float* __restrict__ x,
                                                  const float* __restrict__ b_emb,
                                                  float* __restrict__ outF,
                                                  const u16* __restrict__ wtH,
                                                  const float* __restrict__ bias,
                                                  const u16* __restrict__ sorted,
                                                  const int* __restrict__ offs,
                                                  const float* __restrict__ inv,
                                                  const int* __restrict__ bend) {
    __shared__ __align__(16) u16 hG[128 * HSTR];   // 34816 B current-layer h
    __shared__ __align__(16) u16 sQ[2][4096];      // 16384 B B k-quarter dbuf
    __shared__ u16   sIdx[RR][8 * ICAP];           // 12288 B local src idx (all 4 rels)
    __shared__ float sInv[8 * 64];                 //  2048 B inverse counts
    __shared__ int   sMeta[RR][8][2];              //   256 B (w0,w1)
    __shared__ float red[8][128];                  //  4096 B pool reduce

    int tid  = threadIdx.x;
    int wave = tid >> 6, lane = tid & 63;
    int mm   = lane & 15;            // MFMA m/n lane == gather node index
    int qd   = lane >> 4;            // MFMA quad == gather col-chunk selector
    int gr   = blockIdx.x;           // graph id
    int row0g = gr * NPG;            // global row base
    int strip = wave * 16;           // local node base of this wave
    const u16* wtE = wtH + 163840;   // embed matrix (128 n x 64 k)

    // stage k-quarter `step` into sQ[bufi]: layer mats, row stride 128
    auto stage = [&](int step, int bufi) {
        const u16* src = wtH + (step >> 2) * 16384 + (step & 3) * 32;
        int u = tid;                 // 512 granules, 1/thread
        int n = u >> 2, j = u & 3;
        gl_lds16(src + n * 128 + ((j ^ ((n >> 1) & 3)) * 8), &sQ[bufi][u * 8]);
    };
    // stage embed k-quarter q (K=64 mat, row stride 64)
    auto stageE = [&](int q, int bufi) {
        const u16* src = wtE + q * 32;
        int u = tid;
        int n = u >> 2, j = u & 3;
        gl_lds16(src + n * 64 + ((j ^ ((n >> 1) & 3)) * 8), &sQ[bufi][u * 8]);
    };

    f32x4 acc[8];
    auto mfma_quarter = [&](int bufi, bf16x8 A) {
        const u16* buf = sQ[bufi];
#pragma unroll
        for (int nt = 0; nt < 8; ++nt) {
            int n = nt * 16 + mm;
            int slot = n * 4 + (qd ^ ((n >> 1) & 3));
            bf16x8 B = *(const bf16x8*)&buf[slot * 8];
            acc[nt] = __builtin_amdgcn_mfma_f32_16x16x32_bf16(A, B, acc[nt], 0, 0, 0);
        }
    };

    // A-layout-direct mean-aggregate: lane (mm,qd) does node strip+mm,
    // cols ks*32+qd*8..+7 -> AH[0..3] (the next matrix's A fragment).
    auto gather = [&](int rel, bf16x8* AH) {
        int b = rel * NN + row0g + strip + mm;
        int w0 = sMeta[rel][wave][0];
        int w1 = sMeta[rel][wave][1];
        bool fits = (w1 - w0 <= ICAP);
        const u16* si = &sIdx[rel][wave * ICAP];
        int r0 = offs[b];
        int r1 = (((b + 1) & 1023) == 0) ? bend[b >> 10] : offs[b + 1];
        int o  = r0 - w0;
        int cnt = r1 - r0;

        float ax[32];
#pragma unroll
        for (int i = 0; i < 32; ++i) ax[i] = 0.f;

        auto upk8 = [&](int ks, uint4 u) {
            ax[ks*8+0] += __uint_as_float(u.x << 16);
            ax[ks*8+1] += __uint_as_float(u.x & 0xffff0000u);
            ax[ks*8+2] += __uint_as_float(u.y << 16);
            ax[ks*8+3] += __uint_as_float(u.y & 0xffff0000u);
            ax[ks*8+4] += __uint_as_float(u.z << 16);
            ax[ks*8+5] += __uint_as_float(u.z & 0xffff0000u);
            ax[ks*8+6] += __uint_as_float(u.w << 16);
            ax[ks*8+7] += __uint_as_float(u.w & 0xffff0000u);
        };
        auto eat = [&](int li) {                 // full 128-col row: 4 b128 reads
            int rb = li * HSTR + qd * 8;
            uint4 u0 = *(const uint4*)&hG[rb];
            uint4 u1 = *(const uint4*)&hG[rb + 32];
            uint4 u2 = *(const uint4*)&hG[rb + 64];
            uint4 u3 = *(const uint4*)&hG[rb + 96];
            upk8(0, u0); upk8(1, u1); upk8(2, u2); upk8(3, u3);
        };

        int j = 0;
        if (fits) {
            for (; j + 2 <= cnt; j += 2) {       // 2 edges -> 8 reads in flight
                int i0 = si[o + j], i1 = si[o + j + 1];
                int rb0 = i0 * HSTR + qd * 8, rb1 = i1 * HSTR + qd * 8;
                uint4 a0 = *(const uint4*)&hG[rb0];
                uint4 a1 = *(const uint4*)&hG[rb0 + 32];
                uint4 a2 = *(const uint4*)&hG[rb0 + 64];
                uint4 a3 = *(const uint4*)&hG[rb0 + 96];
                uint4 b0 = *(const uint4*)&hG[rb1];
                uint4 b1 = *(const uint4*)&hG[rb1 + 32];
                uint4 b2 = *(const uint4*)&hG[rb1 + 64];
                uint4 b3 = *(const uint4*)&hG[rb1 + 96];
                upk8(0, a0); upk8(1, a1); upk8(2, a2); upk8(3, a3);
                upk8(0, b0); upk8(1, b1); upk8(2, b2); upk8(3, b3);
            }
            if (j < cnt) eat(si[o + j]);
        } else {
            for (; j < cnt; ++j) eat((int)sorted[r0 + j] & 127);
        }

        float s = sInv[wave * 64 + rel * 16 + mm];
#pragma unroll
        for (int ks = 0; ks < 4; ++ks) {
            uint4 u;
            u.x = bf16_rne(ax[ks*8+0] * s) | (bf16_rne(ax[ks*8+1] * s) << 16);
            u.y = bf16_rne(ax[ks*8+2] * s) | (bf16_rne(ax[ks*8+3] * s) << 16);
            u.z = bf16_rne(ax[ks*8+4] * s) | (bf16_rne(ax[ks*8+5] * s) << 16);
            u.w = bf16_rne(ax[ks*8+6] * s) | (bf16_rne(ax[ks*8+7] * s) << 16);
            AH[ks] = *(bf16x8*)&u;
        }
    };

    // ---- prologue ----
    stageE(0, 0);                                // embed quarter0 DMA
    for (int r = 0; r < RR; ++r) {               // all 4 relations' indices (local)
        int bidx0 = r * NN + row0g + strip;
        int w0 = offs[bidx0];
        int i16 = bidx0 + 16;
        int w1 = ((i16 & 1023) == 0) ? bend[bidx0 >> 10] : offs[i16];
        if (lane == 0) { sMeta[r][wave][0] = w0; sMeta[r][wave][1] = w1; }
        int wcnt = w1 - w0;
        if (wcnt > ICAP) wcnt = ICAP;
        for (int i = lane; i < wcnt; i += 64)
            sIdx[r][wave * ICAP + i] = (u16)(sorted[w0 + i] & 127);
    }
    {   // inv for this wave's 16 nodes x 4 relations
        int r = lane >> 4, node = lane & 15;
        sInv[wave * 64 + lane] = inv[r * NN + row0g + strip + node];
    }
    __syncthreads();                             // embed buf0 DMA drained

    // ---- embed: hG = bf16(x @ W_emb + b_emb), A from global x ----
    {
#pragma unroll
        for (int nt = 0; nt < 8; ++nt) {
            float bv = b_emb[nt * 16 + mm];
            acc[nt] = (f32x4){bv, bv, bv, bv};
        }
        bf16x8 AE[2];
#pragma unroll
        for (int ks = 0; ks < 2; ++ks) {         // k = ks*32 + qd*8 + 0..7
            const float* xp = &x[(size_t)(row0g + strip + mm) * FIN + ks * 32 + qd * 8];
            float4 a = *(const float4*)xp;
            float4 b = *(const float4*)(xp + 4);
            uint4 u;
            u.x = bf16_rne(a.x) | (bf16_rne(a.y) << 16);
            u.y = bf16_rne(a.z) | (bf16_rne(a.w) << 16);
            u.z = bf16_rne(b.x) | (bf16_rne(b.y) << 16);
            u.w = bf16_rne(b.z) | (bf16_rne(b.w) << 16);
            AE[ks] = *(bf16x8*)&u;
        }
        stageE(1, 1);
        mfma_quarter(0, AE[0]);
        __syncthreads();                         // buf1 drained; buf0 free
        stage(0, 0);                             // L0 mat0 q0 -> buf0
        mfma_quarter(1, AE[1]);
        __syncthreads();                         // buf0 drained; buf1 free
#pragma unroll
        for (int nt = 0; nt < 8; ++nt)           // write h0 rows into hG (no relu)
#pragma unroll
            for (int r = 0; r < 4; ++r)
                hG[(strip + qd * 4 + r) * HSTR + nt * 16 + mm] =
                    (u16)bf16_rne(acc[nt][r]);
        __syncthreads();                         // hG visible to all waves
    }

    // ---- two layers x 5 matrices ----
    for (int L = 0; L < 2; ++L) {
        const float* bl = bias + L * DD;
#pragma unroll
        for (int i = 0; i < 8; ++i) acc[i] = (f32x4){0.f, 0.f, 0.f, 0.f};

        bf16x8 AH[4];
#pragma unroll
        for (int ks = 0; ks < 4; ++ks)           // root A direct from hG
            AH[ks] = *(const bf16x8*)&hG[(strip + mm) * HSTR + ks * 32 + qd * 8];

        for (int m = 0; m < 5; ++m) {
#pragma unroll
            for (int q = 0; q < 4; ++q) {
                int step = L * 20 + m * 4 + q;
                if (step + 1 < 40) stage(step + 1, (step + 1) & 1);
                mfma_quarter(step & 1, AH[q]);
                __syncthreads();                 // next buf drained; this buf free
            }
            if (m < 4) gather(m, AH);            // next mat's A, in-register
        }

        if (L == 0) {
            // h1 -> hG (all hG readers done: root-A + gathers precede mat4 barriers)
#pragma unroll
            for (int nt = 0; nt < 8; ++nt) {
                float bv = bl[nt * 16 + mm];
#pragma unroll
                for (int r = 0; r < 4; ++r)
                    hG[(strip + qd * 4 + r) * HSTR + nt * 16 + mm] =
                        (u16)bf16_rne(fmaxf(acc[nt][r] + bv, 0.f));
            }
            __syncthreads();                     // h1 visible to all waves
        } else {
            // max-pool: per-wave column max -> LDS -> plain store
#pragma unroll
            for (int nt = 0; nt < 8; ++nt) {
                float bv = bl[nt * 16 + mm];
                float v = fmaxf(fmaxf(acc[nt][0], acc[nt][1]),
                                fmaxf(acc[nt][2], acc[nt][3])) + bv;
                v = fmaxf(v, 0.f);               // relu(max) == max(relu)
                v = fmaxf(v, __shfl_xor(v, 16));
                v = fmaxf(v, __shfl_xor(v, 32));
                if (lane < 16) red[wave][nt * 16 + mm] = v;
            }
            __syncthreads();
            if (tid < 128) {
                float mx = red[0][tid];
#pragma unroll
                for (int w = 1; w < 8; ++w) mx = fmaxf(mx, red[w][tid]);
                outF[gr * DD + tid] = mx;
            }
        }
    }
}

// ---------------- launch ----------------

extern "C" void kernel_launch(void* const* d_in, const int* in_sizes, int n_in,
                              void* d_out, int out_size, void* d_ws, size_t ws_size,
                              hipStream_t stream) {
    const float* x      = (const float*)d_in[0];
    const int*   ei     = (const int*)  d_in[1];
    const int*   ea     = (const int*)  d_in[2];
    const float* W_emb  = (const float*)d_in[3];
    const float* b_emb  = (const float*)d_in[4];
    const float* W_root = (const float*)d_in[5];
    const float* W_rel  = (const float*)d_in[6];
    const float* bias   = (const float*)d_in[7];
    float* out = (float*)d_out;

    char* p = (char*)d_ws;
    u32*      bcur   = (u32*)p;      p += 1024;                     // bucket cursors (memset 0)
    int*      bend   = (int*)p;      p += 1024;                     // bucket end sentinels
    float*    inv    = (float*)p;    p += (size_t)NRSEG * 4;        // 1 MB
    int*      offs   = (int*)p;      p += (size_t)NRSEG * 4;        // 1 MB
    u32*      binned = (u32*)p;      p += (size_t)256 * BSZ * 4;    // 8.39 MB static slices
    u16*      sorted = (u16*)p;      p += (size_t)256 * BSZ * 2;    // 4.19 MB static slices
    u16*      wtH    = (u16*)p;      p += (size_t)(10 * 16384 + 8192) * 2;  // 0.35 MB (+wtE)

    hipMemsetAsync(bcur, 0, 1024, stream);

    k_front<<<864, 256, 0, stream>>>(ei, ea, bcur, binned,
                                     W_root, W_rel, W_emb, wtH);
    k_binB <<<256, 256, 0, stream>>>(binned, bcur, offs, inv, sorted, bend);
    k_fused<<<GG, 512, 0, stream>>>(x, b_emb, out, wtH, bias,
                                    sorted, offs, inv, bend);
}

// Round 17
// 188.025 us; speedup vs baseline: 1.7556x; 1.1075x over previous
//
#include <hip/hip_runtime.h>

// Problem constants
constexpr int GG    = 512;          // graphs
constexpr int NPG   = 128;          // nodes per graph
constexpr int FIN   = 64;
constexpr int DD    = 128;
constexpr int RR    = 4;
constexpr int NN    = GG * NPG;     // 65536 nodes
constexpr int EE    = 1572864;      // edges
constexpr int SLC   = 4096;         // per-graph record slice (avg 3072, sd ~55)
constexpr int HSTR  = 136;          // hG padded row stride in u16 (68 dwords)

typedef __attribute__((ext_vector_type(8))) short bf16x8;
typedef __attribute__((ext_vector_type(4))) float f32x4;
typedef unsigned short u16;
typedef unsigned int   u32;

__device__ __forceinline__ u32 bf16_rne(float x) {
    u32 u = __float_as_uint(x);
    return (u + 0x7FFFu + ((u >> 16) & 1u)) >> 16;
}

// async global->LDS DMA, 16 B per lane; LDS side must be uniform-base + lane*16
__device__ __forceinline__ void gl_lds16(const void* g, void* l) {
    __builtin_amdgcn_global_load_lds((const __attribute__((address_space(1))) u32*)g,
                                     (__attribute__((address_space(3))) u32*)l, 16, 0, 0);
}

// ---------------- front: binA (graph buckets, u16 recs) + prep ---------------
// blocks [0,192): binA | [192,832): prep 10 layer mats | [832,864): prep wtE.
// rec = locSrc(7) | loc(7)<<7 | rel(2)<<14 — edges are within-graph so 16 bits
// suffice. Recs staged in LDS so ei/ea are read ONCE (19 MB vs 31 MB).

__global__ __launch_bounds__(256, 2) void k_front(const int* __restrict__ ei,
                                                  const int* __restrict__ ea,
                                                  u32* __restrict__ bcur,
                                                  u16* __restrict__ binned,
                                                  const float* __restrict__ W_root,
                                                  const float* __restrict__ W_rel,
                                                  const float* __restrict__ W_emb,
                                                  u16* __restrict__ wtH) {
    __shared__ u32 sRec[8192];                 // 32 KB staged rec|bucket
    __shared__ int bh[512];
    __shared__ int lcur[512];
    int tid = threadIdx.x;
    int bid = blockIdx.x;

    if (bid < 192) {
        int e0 = bid * 8192;                   // 192 blocks cover EE exactly
        bh[tid] = 0; bh[tid + 256] = 0;
        __syncthreads();
        for (int i = 0; i < 32; ++i) {
            int e = e0 + i * 256 + tid;
            int src = ei[e];
            int dst = ei[EE + e];
            int a   = ea[e];
            int g   = dst >> 7;                // graph id = bucket
            u32 rec = (u32)(src & 127) | ((u32)(dst & 127) << 7) | ((u32)a << 14);
            sRec[i * 256 + tid] = rec | ((u32)g << 16);
            atomicAdd(&bh[g], 1);
        }
        __syncthreads();
        lcur[tid]       = tid * SLC +
                          (int)atomicAdd(&bcur[tid], (u32)bh[tid]);
        lcur[tid + 256] = (tid + 256) * SLC +
                          (int)atomicAdd(&bcur[tid + 256], (u32)bh[tid + 256]);
        __syncthreads();
        for (int i = 0; i < 32; ++i) {
            u32 r = sRec[i * 256 + tid];
            int pos = atomicAdd(&lcur[r >> 16], 1);
            binned[pos] = (u16)(r & 0xFFFFu);
        }
    } else if (bid < 832) {
        // ---- prep: transpose layer weights to bf16, wt[mat*16384 + n*128 + k] ----
        int idx = (bid - 192) * 256 + tid;     // covers 10*16384
        int mat = idx >> 14;
        int rem = idx & 16383;
        int n = rem >> 7, k = rem & 127;
        int l = mat / 5, m5 = mat - l * 5;
        float v = (m5 == 0) ? W_root[l * 16384 + k * 128 + n]
                            : W_rel[((l * RR + (m5 - 1)) * 128 + k) * 128 + n];
        wtH[idx] = (u16)bf16_rne(v);
    } else {
        // ---- prep wtE = W_emb^T (128 n x 64 k) at wtH + 163840 ----
        int idx = (bid - 832) * 256 + tid;     // covers 8192
        int n = idx >> 6, k = idx & 63;
        wtH[163840 + idx] = (u16)bf16_rne(W_emb[k * DD + n]);
    }
}

// ---------------- fused sort + embed + two-layer RGCN + max-pool -------------
// One block per graph, 512 threads = 8 waves; wave owns a 16-node M-strip.
// Prologue counting-sorts the graph's own rec slice entirely in LDS/registers
// (hist over 512 keys = rel*128+loc, scan, rank) -> sIdx/sOffs/sInv. No
// global offs/inv/sorted arrays, no binB kernel. Gather is A-layout-direct
// in TWO 64-col halves (ax[16] + 4 temps: fits the register file — the r16
// single-pass ax[32] version spilled 17.9 MB to scratch). Same total LDS
// reads (4 b128/edge). LDS ~69.6 KB -> 2 blocks/CU.

__global__ __launch_bounds__(512, 4) void k_fused(const float* __restrict__ x,
                                                  const float* __restrict__ b_emb,
                                                  float* __restrict__ outF,
                                                  const u16* __restrict__ wtH,
                                                  const float* __restrict__ bias,
                                                  const u16* __restrict__ binned,
                                                  const u32* __restrict__ bcur) {
    __shared__ __align__(16) u16 hG[128 * HSTR];   // 34816 B current-layer h
    __shared__ __align__(16) u16 sQ[2][4096];      // 16384 B B k-quarter dbuf
    __shared__ u16   sIdx[SLC];                    //  8192 B sorted local src
    __shared__ int   sOffs[513];                   //  2052 B segment starts + sentinel
    __shared__ int   sCnt[512];                    //  2048 B hist / rank cursor
    __shared__ float sInv[512];                    //  2048 B inverse counts
    __shared__ float red[8][128];                  //  4096 B pool reduce

    int tid  = threadIdx.x;
    int wave = tid >> 6, lane = tid & 63;
    int mm   = lane & 15;            // MFMA m/n lane == gather node index
    int qd   = lane >> 4;            // MFMA quad == gather col-chunk selector
    int gr   = blockIdx.x;           // graph id
    int row0g = gr * NPG;            // global row base
    int strip = wave * 16;           // local node base of this wave
    const u16* wtE = wtH + 163840;   // embed matrix (128 n x 64 k)

    // stage k-quarter `step` into sQ[bufi]: layer mats, row stride 128
    auto stage = [&](int step, int bufi) {
        const u16* src = wtH + (step >> 2) * 16384 + (step & 3) * 32;
        int u = tid;                 // 512 granules, 1/thread
        int n = u >> 2, j = u & 3;
        gl_lds16(src + n * 128 + ((j ^ ((n >> 1) & 3)) * 8), &sQ[bufi][u * 8]);
    };
    // stage embed k-quarter q (K=64 mat, row stride 64)
    auto stageE = [&](int q, int bufi) {
        const u16* src = wtE + q * 32;
        int u = tid;
        int n = u >> 2, j = u & 3;
        gl_lds16(src + n * 64 + ((j ^ ((n >> 1) & 3)) * 8), &sQ[bufi][u * 8]);
    };

    f32x4 acc[8];
    auto mfma_quarter = [&](int bufi, bf16x8 A) {
        const u16* buf = sQ[bufi];
#pragma unroll
        for (int nt = 0; nt < 8; ++nt) {
            int n = nt * 16 + mm;
            int slot = n * 4 + (qd ^ ((n >> 1) & 3));
            bf16x8 B = *(const bf16x8*)&buf[slot * 8];
            acc[nt] = __builtin_amdgcn_mfma_f32_16x16x32_bf16(A, B, acc[nt], 0, 0, 0);
        }
    };

    // A-layout-direct mean-aggregate, TWO 64-col halves to stay in registers.
    auto gather = [&](int rel, bf16x8* AH) {
        int key = (rel << 7) + strip + mm;
        int r0 = sOffs[key];
        int r1 = sOffs[key + 1];
        float s = sInv[key];
#pragma unroll
        for (int h = 0; h < 2; ++h) {
            int cb = h * 64 + qd * 8;
            float ax[16];
#pragma unroll
            for (int i = 0; i < 16; ++i) ax[i] = 0.f;
            auto upk8 = [&](int ks, uint4 u) {
                ax[ks*8+0] += __uint_as_float(u.x << 16);
                ax[ks*8+1] += __uint_as_float(u.x & 0xffff0000u);
                ax[ks*8+2] += __uint_as_float(u.y << 16);
                ax[ks*8+3] += __uint_as_float(u.y & 0xffff0000u);
                ax[ks*8+4] += __uint_as_float(u.z << 16);
                ax[ks*8+5] += __uint_as_float(u.z & 0xffff0000u);
                ax[ks*8+6] += __uint_as_float(u.w << 16);
                ax[ks*8+7] += __uint_as_float(u.w & 0xffff0000u);
            };
            int j = r0;
            for (; j + 2 <= r1; j += 2) {        // 2 edges -> 4 reads in flight
                int rb0 = (int)sIdx[j]     * HSTR + cb;
                int rb1 = (int)sIdx[j + 1] * HSTR + cb;
                uint4 a0 = *(const uint4*)&hG[rb0];
                uint4 a1 = *(const uint4*)&hG[rb0 + 32];
                uint4 b0 = *(const uint4*)&hG[rb1];
                uint4 b1 = *(const uint4*)&hG[rb1 + 32];
                upk8(0, a0); upk8(1, a1); upk8(0, b0); upk8(1, b1);
            }
            if (j < r1) {
                int rb = (int)sIdx[j] * HSTR + cb;
                uint4 a0 = *(const uint4*)&hG[rb];
                uint4 a1 = *(const uint4*)&hG[rb + 32];
                upk8(0, a0); upk8(1, a1);
            }
#pragma unroll
            for (int k2 = 0; k2 < 2; ++k2) {
                uint4 u;
                u.x = bf16_rne(ax[k2*8+0] * s) | (bf16_rne(ax[k2*8+1] * s) << 16);
                u.y = bf16_rne(ax[k2*8+2] * s) | (bf16_rne(ax[k2*8+3] * s) << 16);
                u.z = bf16_rne(ax[k2*8+4] * s) | (bf16_rne(ax[k2*8+5] * s) << 16);
                u.w = bf16_rne(ax[k2*8+6] * s) | (bf16_rne(ax[k2*8+7] * s) << 16);
                AH[h * 2 + k2] = *(bf16x8*)&u;
            }
        }
    };

    // ---- prologue: in-LDS counting sort of this graph's rec slice ----
    stageE(0, 0);                                // embed quarter0 DMA (sQ unused by sort)
    int cnt = (int)bcur[gr];
    if (cnt > SLC) cnt = SLC;                    // never in practice (18 sigma)
    uint4 myRec = *(const uint4*)&binned[gr * SLC + tid * 8];   // 8 recs/thread
    sCnt[tid] = 0;
    __syncthreads();
    int base8 = tid * 8;
#pragma unroll
    for (int i = 0; i < 8; ++i) {
        if (base8 + i < cnt) {
            u32 w = ((const u32*)&myRec)[i >> 1];
            u32 rec = (i & 1) ? (w >> 16) : (w & 0xFFFFu);
            atomicAdd(&sCnt[rec >> 7], 1);
        }
    }
    __syncthreads();
    int c = sCnt[tid];
    sOffs[tid] = c;
    __syncthreads();
    for (int o = 1; o < 512; o <<= 1) {          // inclusive scan over 512 keys
        int t = (tid >= o) ? sOffs[tid - o] : 0;
        __syncthreads();
        sOffs[tid] += t;
        __syncthreads();
    }
    int ex = sOffs[tid] - c;
    sOffs[tid] = ex;
    sCnt[tid]  = ex;                             // rank cursor
    sInv[tid]  = 1.0f / (float)(c > 0 ? c : 1);
    if (tid == 0) sOffs[512] = cnt;
    __syncthreads();
#pragma unroll
    for (int i = 0; i < 8; ++i) {                // rank-scatter local src indices
        if (base8 + i < cnt) {
            u32 w = ((const u32*)&myRec)[i >> 1];
            u32 rec = (i & 1) ? (w >> 16) : (w & 0xFFFFu);
            int pos = atomicAdd(&sCnt[rec >> 7], 1);
            sIdx[pos] = (u16)(rec & 127u);
        }
    }
    __syncthreads();                             // sort done; embed buf0 drained

    // ---- embed: hG = bf16(x @ W_emb + b_emb), A from global x ----
    {
#pragma unroll
        for (int nt = 0; nt < 8; ++nt) {
            float bv = b_emb[nt * 16 + mm];
            acc[nt] = (f32x4){bv, bv, bv, bv};
        }
        bf16x8 AE[2];
#pragma unroll
        for (int ks = 0; ks < 2; ++ks) {         // k = ks*32 + qd*8 + 0..7
            const float* xp = &x[(size_t)(row0g + strip + mm) * FIN + ks * 32 + qd * 8];
            float4 a = *(const float4*)xp;
            float4 b = *(const float4*)(xp + 4);
            uint4 u;
            u.x = bf16_rne(a.x) | (bf16_rne(a.y) << 16);
            u.y = bf16_rne(a.z) | (bf16_rne(a.w) << 16);
            u.z = bf16_rne(b.x) | (bf16_rne(b.y) << 16);
            u.w = bf16_rne(b.z) | (bf16_rne(b.w) << 16);
            AE[ks] = *(bf16x8*)&u;
        }
        stageE(1, 1);
        mfma_quarter(0, AE[0]);
        __syncthreads();                         // buf1 drained; buf0 free
        stage(0, 0);                             // L0 mat0 q0 -> buf0
        mfma_quarter(1, AE[1]);
        __syncthreads();                         // buf0 drained; buf1 free
#pragma unroll
        for (int nt = 0; nt < 8; ++nt)           // write h0 rows into hG (no relu)
#pragma unroll
            for (int r = 0; r < 4; ++r)
                hG[(strip + qd * 4 + r) * HSTR + nt * 16 + mm] =
                    (u16)bf16_rne(acc[nt][r]);
        __syncthreads();                         // hG visible to all waves
    }

    // ---- two layers x 5 matrices ----
    for (int L = 0; L < 2; ++L) {
        const float* bl = bias + L * DD;
#pragma unroll
        for (int i = 0; i < 8; ++i) acc[i] = (f32x4){0.f, 0.f, 0.f, 0.f};

        bf16x8 AH[4];
#pragma unroll
        for (int ks = 0; ks < 4; ++ks)           // root A direct from hG
            AH[ks] = *(const bf16x8*)&hG[(strip + mm) * HSTR + ks * 32 + qd * 8];

        for (int m = 0; m < 5; ++m) {
#pragma unroll
            for (int q = 0; q < 4; ++q) {
                int step = L * 20 + m * 4 + q;
                if (step + 1 < 40) stage(step + 1, (step + 1) & 1);
                mfma_quarter(step & 1, AH[q]);
                __syncthreads();                 // next buf drained; this buf free
            }
            if (m < 4) gather(m, AH);            // next mat's A, in-register
        }

        if (L == 0) {
            // h1 -> hG (all hG readers done: root-A + gathers precede mat4 barriers)
#pragma unroll
            for (int nt = 0; nt < 8; ++nt) {
                float bv = bl[nt * 16 + mm];
#pragma unroll
                for (int r = 0; r < 4; ++r)
                    hG[(strip + qd * 4 + r) * HSTR + nt * 16 + mm] =
                        (u16)bf16_rne(fmaxf(acc[nt][r] + bv, 0.f));
            }
            __syncthreads();                     // h1 visible to all waves
        } else {
            // max-pool: per-wave column max -> LDS -> plain store
#pragma unroll
            for (int nt = 0; nt < 8; ++nt) {
                float bv = bl[nt * 16 + mm];
                float v = fmaxf(fmaxf(acc[nt][0], acc[nt][1]),
                                fmaxf(acc[nt][2], acc[nt][3])) + bv;
                v = fmaxf(v, 0.f);               // relu(max) == max(relu)
                v = fmaxf(v, __shfl_xor(v, 16));
                v = fmaxf(v, __shfl_xor(v, 32));
                if (lane < 16) red[wave][nt * 16 + mm] = v;
            }
            __syncthreads();
            if (tid < 128) {
                float mx = red[0][tid];
#pragma unroll
                for (int w = 1; w < 8; ++w) mx = fmaxf(mx, red[w][tid]);
                outF[gr * DD + tid] = mx;
            }
        }
    }
}

// ---------------- launch ----------------

extern "C" void kernel_launch(void* const* d_in, const int* in_sizes, int n_in,
                              void* d_out, int out_size, void* d_ws, size_t ws_size,
                              hipStream_t stream) {
    const float* x      = (const float*)d_in[0];
    const int*   ei     = (const int*)  d_in[1];
    const int*   ea     = (const int*)  d_in[2];
    const float* W_emb  = (const float*)d_in[3];
    const float* b_emb  = (const float*)d_in[4];
    const float* W_root = (const float*)d_in[5];
    const float* W_rel  = (const float*)d_in[6];
    const float* bias   = (const float*)d_in[7];
    float* out = (float*)d_out;

    char* p = (char*)d_ws;
    u32* bcur   = (u32*)p; p += 2048;                               // 512 cursors (memset 0)
    u16* binned = (u16*)p; p += (size_t)GG * SLC * 2;               // 4.19 MB static slices
    u16* wtH    = (u16*)p; p += (size_t)(10 * 16384 + 8192) * 2;    // 0.35 MB (+wtE)

    hipMemsetAsync(bcur, 0, 2048, stream);

    k_front<<<864, 256, 0, stream>>>(ei, ea, bcur, binned,
                                     W_root, W_rel, W_emb, wtH);
    k_fused<<<GG, 512, 0, stream>>>(x, b_emb, out, wtH, bias, binned, bcur);
}